// Round 9
// baseline (856.680 us; speedup 1.0000x reference)
//
#include <hip/hip_runtime.h>
#include <cstdint>

#define HID 128

static constexpr int kNOp = 50000, kNMa = 1000, kNJob = 5000;
static constexpr int kNTot = 56000;                 // op | ma | job global node space
static constexpr int kETot = 600000;
static constexpr int kSeg = 156000;                 // (dst,relation) sub-segments
static constexpr int kEsz[5]   = {150000, 100000, 150000, 100000, 100000};
static constexpr int kSrcT[5]  = {0, 0, 1, 2, 0};
static constexpr int kDstT[5]  = {0, 1, 0, 0, 2};
static constexpr int kNodeOff[3] = {0, 50000, 51000};
static constexpr int kSoff[5]  = {0, 0, 50000, 51000, 0};
static constexpr int kDoff[5]  = {0, 50000, 0, 0, 51000};
static constexpr int kEoff[6]  = {0, 150000, 250000, 400000, 500000, 600000};
static constexpr int kRoff[5]  = {0, 50000, 100000, 101000, 106000};  // xs_all row offset (src counts)
static constexpr int kRTot = 156000;

typedef __attribute__((ext_vector_type(8))) __bf16 bf16x8;
typedef __attribute__((ext_vector_type(4))) float f32x4;

__device__ inline unsigned short f2b(float f) {
  unsigned u = __float_as_uint(f);
  unsigned r = (u + 0x7FFFu + ((u >> 16) & 1u)) >> 16;
  return (unsigned short)r;
}
__device__ inline float b2f(unsigned short u) {
  return __uint_as_float(((unsigned)u) << 16);
}

// (dst,relation) -> softmax sub-segment id; op sub-segments contiguous per node
__device__ inline int seg_of(int t, int d) {
  if (t == 0) return 3 * d;
  if (t == 2) return 3 * d + 1;
  if (t == 3) return 3 * d + 2;
  if (t == 1) return 150000 + d;
  return 151000 + d;  // t4
}

// ------------------------------------------------ fp32 -> bf16 (pad K to Kp)
__global__ void conv_pad(const float* __restrict__ in, unsigned short* __restrict__ out,
                         int M, int K, int Kp) {
  int i = blockIdx.x * blockDim.x + threadIdx.x;
  if (i >= M * Kp) return;
  int r = i / Kp, c = i - r * Kp;
  out[i] = (c < K) ? f2b(in[(size_t)r * K + c]) : (unsigned short)0;
}

// ---------------------- W[K x N] fp32 -> Wt[N x Kp] bf16 (batched, zero-pad K)
__global__ void transpose_w(const float* __restrict__ W, unsigned short* __restrict__ Wt,
                            int K, int N, int Kp, int nmat) {
  int i = blockIdx.x * blockDim.x + threadIdx.x;
  int per = N * Kp;
  if (i >= nmat * per) return;
  int b = i / per, rem = i - b * per;
  int n = rem / Kp, k = rem - n * Kp;
  Wt[i] = (k < K) ? f2b(W[(size_t)b * K * N + (size_t)k * N + n]) : (unsigned short)0;
}

// --------------------------------------------- plain bf16 MFMA GEMM (N=128)
// OPERAND-SWAPPED: acc = mfma(W_frag, x_frag) -> D[wcol][xrow]; each thread
// holds 4 CONSECUTIVE output cols of one x-row -> float4/ushort4 stores.
template <int KC>   // K = KC*32
__global__ __launch_bounds__(256) void gemm_mfma(
    const unsigned short* __restrict__ A, const unsigned short* __restrict__ Bt,
    const float* __restrict__ bias, float* __restrict__ Cf,
    unsigned short* __restrict__ Cb, int M) {
  const int K = KC * 32;
  int w = blockIdx.x * 4 + (threadIdx.x >> 6);
  int m0 = w * 16;
  if (m0 >= M) return;
  int lane = threadIdx.x & 63;
  int l16 = lane & 15, quad = lane >> 4;
  int xrow = m0 + l16; if (xrow >= M) xrow = M - 1;
  bf16x8 xf[KC];
#pragma unroll
  for (int kc = 0; kc < KC; kc++) {
    int4 raw = *(const int4*)(A + (size_t)xrow * K + kc * 32 + quad * 8);
    xf[kc] = __builtin_bit_cast(bf16x8, raw);
  }
  bool wr = (m0 + l16 < M);
  int row = m0 + l16;
#pragma unroll
  for (int nt = 0; nt < 8; nt++) {
    f32x4 acc = {0.f, 0.f, 0.f, 0.f};
#pragma unroll
    for (int kc = 0; kc < KC; kc++) {
      int4 braw = *(const int4*)(Bt + (size_t)(nt * 16 + l16) * K + kc * 32 + quad * 8);
      acc = __builtin_amdgcn_mfma_f32_16x16x32_bf16(
          __builtin_bit_cast(bf16x8, braw), xf[kc], acc, 0, 0, 0);
    }
    int col0 = nt * 16 + quad * 4;
    float o[4];
#pragma unroll
    for (int r = 0; r < 4; r++) o[r] = acc[r] + (bias ? bias[col0 + r] : 0.f);
    if (wr) {
      if (Cf) *(float4*)(Cf + (size_t)row * HID + col0) = make_float4(o[0], o[1], o[2], o[3]);
      if (Cb) *(ushort4*)(Cb + (size_t)row * HID + col0) =
                  make_ushort4(f2b(o[0]), f2b(o[1]), f2b(o[2]), f2b(o[3]));
    }
  }
}

// ------------- fused xs GEMM with LDS-staged weights + LDS-bounced stores.
// Block = 64 rows (4 waves x 16). Per relation: Wg[t] (32KB) staged ONCE per
// block into LDS; out tiles bounced through LDS -> 4 x 1KB coalesced stores.
__global__ __launch_bounds__(256) void gemm_xs(const unsigned short* __restrict__ x,
                                               const unsigned short* __restrict__ WgTl,
                                               unsigned short* __restrict__ xs) {
  __shared__ __align__(16) unsigned short Bs[128 * 136];    // +16B row pad (bank)
  __shared__ __align__(16) unsigned short Os[4][16 * 136];
  // blocks [0,782): op; [782,798): ma; [798,877): job  (64 rows per block)
  int b = blockIdx.x;
  int grp = (b < 782) ? 0 : (b < 798 ? 1 : 2);
  int sb   = (grp == 0) ? 0     : (grp == 1 ? 782   : 798);
  int M    = (grp == 0) ? 50000 : (grp == 1 ? 1000  : 5000);
  int xoff = (grp == 0) ? 0     : (grp == 1 ? 50000 : 51000);
  int tid = threadIdx.x;
  int wid = tid >> 6, lane = tid & 63;
  int l16 = lane & 15, quad = lane >> 4;
  int m0 = (b - sb) * 64 + wid * 16;
  int xrow = m0 + l16; if (xrow >= M) xrow = M - 1;
  bf16x8 xf[4];
#pragma unroll
  for (int kc = 0; kc < 4; kc++) {
    int4 raw = *(const int4*)(x + (size_t)(xoff + xrow) * HID + kc * 32 + quad * 8);
    xf[kc] = __builtin_bit_cast(bf16x8, raw);
  }
  int nrel = (grp == 0) ? 3 : 1;
  int rel0  = (grp == 0) ? 0 : (grp == 1 ? 2 : 3);
  int roff0 = (grp == 0) ? 0 : (grp == 1 ? 100000 : 101000);
  int rels[3]  = {rel0, 1, 4};
  int roffs[3] = {roff0, 50000, 106000};
  for (int rr = 0; rr < nrel; rr++) {
    int t = rels[rr];
    unsigned short* Cb = xs + (size_t)roffs[rr] * HID;
    __syncthreads();   // all waves done reading previous Bs
    const unsigned short* Wsrc = WgTl + (size_t)t * HID * HID;
    for (int c = tid; c < 2048; c += 256) {       // 2048 x int4 = 32KB, coalesced
      int row = c >> 4, k8 = c & 15;
      *(int4*)&Bs[row * 136 + k8 * 8] = *(const int4*)(Wsrc + row * 128 + k8 * 8);
    }
    __syncthreads();
#pragma unroll
    for (int nt = 0; nt < 8; nt++) {
      f32x4 acc = {0.f, 0.f, 0.f, 0.f};
#pragma unroll
      for (int kc = 0; kc < 4; kc++) {
        bf16x8 bfr = *(const bf16x8*)&Bs[(nt * 16 + l16) * 136 + kc * 32 + quad * 8];
        acc = __builtin_amdgcn_mfma_f32_16x16x32_bf16(bfr, xf[kc], acc, 0, 0, 0);
      }
      *(ushort4*)&Os[wid][l16 * 136 + nt * 16 + quad * 4] =
          make_ushort4(f2b(acc[0]), f2b(acc[1]), f2b(acc[2]), f2b(acc[3]));
    }
    // wave-private tile -> global, 4 x 1KB contiguous store instructions
#pragma unroll
    for (int i = 0; i < 4; i++) {
      int g = i * 1024 + lane * 16;     // byte offset within the 4KB tile
      int row = g >> 8;
      int colb = g & 255;
      int4 v = *(const int4*)((const char*)&Os[wid][0] + row * 272 + colb);
      if (m0 + row < M)
        *(int4*)((char*)(Cb + (size_t)(m0 + row) * HID) + colb) = v;
    }
  }
}

// ---------------- AS GEMM: AS[M x NCOL] = x[M x 128] @ VbT^T, fp32 out
// (operand-swapped -> float4 coalesced stores)
template <int NCOL>
__global__ __launch_bounds__(256) void gemm_as(
    const unsigned short* __restrict__ A, const unsigned short* __restrict__ Bt,
    float* __restrict__ out, int M) {
  int w = blockIdx.x * 4 + (threadIdx.x >> 6);
  int m0 = w * 16;
  if (m0 >= M) return;
  int lane = threadIdx.x & 63;
  int l16 = lane & 15, quad = lane >> 4;
  int xrow = m0 + l16; if (xrow >= M) xrow = M - 1;
  bf16x8 xf[4];
#pragma unroll
  for (int kc = 0; kc < 4; kc++) {
    int4 raw = *(const int4*)(A + (size_t)xrow * HID + kc * 32 + quad * 8);
    xf[kc] = __builtin_bit_cast(bf16x8, raw);
  }
  bool wr = (m0 + l16 < M);
  int row = m0 + l16;
#pragma unroll
  for (int nt = 0; nt < NCOL / 16; nt++) {
    f32x4 acc = {0.f, 0.f, 0.f, 0.f};
#pragma unroll
    for (int kc = 0; kc < 4; kc++) {
      int4 braw = *(const int4*)(Bt + (size_t)(nt * 16 + l16) * HID + kc * 32 + quad * 8);
      acc = __builtin_amdgcn_mfma_f32_16x16x32_bf16(
          __builtin_bit_cast(bf16x8, braw), xf[kc], acc, 0, 0, 0);
    }
    if (wr) {
      int col0 = nt * 16 + quad * 4;
      *(float4*)(out + (size_t)row * NCOL + col0) = make_float4(acc[0], acc[1], acc[2], acc[3]);
    }
  }
}

// ------------------------------------------------- fold attention vectors
// S[lt,h,k] = sum_c Wg[k][hC+c]*att_s[hC+c]; D likewise; w32/cvec edge fold.
__global__ void fold_kernel(const float* __restrict__ Wg, const float* __restrict__ att_s,
                            const float* __restrict__ att_d, const float* __restrict__ Wge,
                            const float* __restrict__ att_e, const float* __restrict__ Wep,
                            const float* __restrict__ bep,
                            float* __restrict__ S, float* __restrict__ D,
                            float* __restrict__ w32, float* __restrict__ cvec) {
  int idx = blockIdx.x;          // (l*5+t)*8 + h
  int h = idx & 7, lt = idx >> 3;
  int l = lt / 5;
  int H = (l < 2) ? 8 : 1, C = HID / H;
  if (h >= H) return;
  int k = threadIdx.x;           // 0..127
  int t = lt % 5;
  const float* wg  = Wg  + (size_t)lt * HID * HID;
  const float* wge = Wge + (size_t)lt * HID * HID;
  const float* as_ = att_s + (size_t)lt * HID + h * C;
  const float* ad_ = att_d + (size_t)lt * HID + h * C;
  const float* ae_ = att_e + (size_t)lt * HID + h * C;
  float s = 0.f, d = 0.f, v = 0.f;
  for (int c = 0; c < C; c++) {
    float wr = wg[(size_t)k * HID + h * C + c];
    s += wr * as_[c];
    d += wr * ad_[c];
    v += wge[(size_t)k * HID + h * C + c] * ae_[c];
  }
  S[(size_t)idx * HID + k] = s;
  D[(size_t)idx * HID + k] = d;
  __shared__ float vs[HID];
  vs[k] = v;
  __syncthreads();
  if (k < 32) {
    const float* wp = Wep + (size_t)t * 32 * HID + (size_t)k * HID;
    float a = 0.f;
    for (int j = 0; j < HID; j++) a += wp[j] * vs[j];
    w32[(size_t)idx * 32 + k] = a;
  }
  if (k == 32) {
    const float* bp = bep + (size_t)t * HID;
    float a = 0.f;
    for (int j = 0; j < HID; j++) a += bp[j] * vs[j];
    cvec[idx] = a;
  }
}

// ------ pack folded S/D vectors into bf16 Bt layout: VbT[l][col][k], col=(v,h)
// v in 0..9: v<5 -> S of relation v; v>=5 -> D of relation v-5. 80 cols/layer.
__global__ void build_vb(const float* __restrict__ Sv, const float* __restrict__ Dv,
                         unsigned short* __restrict__ VbT) {
  int i = blockIdx.x * 256 + threadIdx.x;
  if (i >= 3 * 80 * HID) return;
  int l = i / (80 * HID), rem = i % (80 * HID);
  int col = rem / HID, k = rem % HID;
  int H = (l < 2) ? 8 : 1;
  float val = 0.f;
  if (col < 10 * H) {
    int v = col / H, h = col % H;
    const float* base = (v < 5) ? Sv : Dv;
    int t = (v < 5) ? v : v - 5;
    val = base[((size_t)(l * 5 + t) * 8 + h) * HID + k];
  }
  VbT[i] = f2b(val);
}

// ---- build the fold-GEMM B matrix: Wf[t][col 0..31][k 0..31] bf16 hi/lo.
// col 0-7 = layer0 heads, 8-15 = layer1 heads, 16 = layer2, 17-31 = zero.
// hi/lo split: w = b2f(hi) + b2f(lo) + O(2^-18 |w|) -> 3-term MFMA product
// keeps fp32-level accuracy while using the matrix pipe.
__global__ void build_wf(const float* __restrict__ w32, const float* __restrict__ cv,
                         unsigned short* __restrict__ Wfh, unsigned short* __restrict__ Wfl,
                         float* __restrict__ ccv) {
  int i = blockIdx.x * 256 + threadIdx.x;
  if (i >= 5 * 32 * 32) return;
  int t = i >> 10, rem = i & 1023;
  int col = rem >> 5, k = rem & 31;
  float val = 0.f, c = 0.f;
  if (col < 8)        { val = w32[((size_t)((0 * 5 + t) * 8 + col)) * 32 + k];       c = cv[(0 * 5 + t) * 8 + col]; }
  else if (col < 16)  { val = w32[((size_t)((1 * 5 + t) * 8 + (col - 8))) * 32 + k]; c = cv[(1 * 5 + t) * 8 + col - 8]; }
  else if (col == 16) { val = w32[((size_t)((2 * 5 + t) * 8 + 0)) * 32 + k];         c = cv[(2 * 5 + t) * 8]; }
  unsigned short h = f2b(val);
  Wfh[i] = h;
  Wfl[i] = f2b(val - b2f(h));
  if (k == 0) ccv[t * 32 + col] = c;
}

// ------------------------------------------------------------ CSR building
struct EdgeJobs {
  const int* src[5]; const int* dst[5];
};

// histogram AND rank in ONE atomic pass: atomicAdd's return value IS the rank.
__global__ void hist_rank(EdgeJobs J, int* __restrict__ cnt, int* __restrict__ rank) {
  int e = blockIdx.x * 256 + threadIdx.x;
  if (e >= kETot) return;
  int t = 0;
  while (t < 4 && e >= kEoff[t + 1]) t++;
  int d = J.dst[t][e - kEoff[t]];
  rank[e] = atomicAdd(&cnt[seg_of(t, d)], 1);
}

// scatter: atomic-free. p = rs[seg] + rank[e]; one packed 16B store per edge.
__global__ void scatter_b(EdgeJobs J, const int* __restrict__ rs,
                          const int* __restrict__ rank, int4* __restrict__ edat) {
  int e = blockIdx.x * 256 + threadIdx.x;
  if (e >= kETot) return;
  int t = 0;
  while (t < 4 && e >= kEoff[t + 1]) t++;
  int el = e - kEoff[t];
  int s = J.src[t][el];
  int d = J.dst[t][el];
  int p = rs[seg_of(t, d)] + rank[e];
  edat[p] = make_int4(e, ((s + kSoff[t]) << 3) | t, ((d + kDoff[t]) << 3) | t,
                      s + kRoff[t]);
}

__global__ void scan_blocks(const int* __restrict__ in, int* __restrict__ out,
                            int* __restrict__ bsums, int n) {
  __shared__ int sh[256];
  int t = threadIdx.x;
  int base = blockIdx.x * 1024 + t * 4;
  int v[4]; int s = 0;
#pragma unroll
  for (int j = 0; j < 4; j++) { v[j] = (base + j < n) ? in[base + j] : 0; s += v[j]; }
  sh[t] = s;
  __syncthreads();
  for (int off = 1; off < 256; off <<= 1) {
    int x = (t >= off) ? sh[t - off] : 0;
    __syncthreads();
    sh[t] += x;
    __syncthreads();
  }
  int run = sh[t] - s;
#pragma unroll
  for (int j = 0; j < 4; j++) { if (base + j < n) out[base + j] = run; run += v[j]; }
  if (t == 255) bsums[blockIdx.x] = sh[255];
}

__global__ void scan_carry(int* bsums, int nb, int* sentinel) {
  if (threadIdx.x == 0 && blockIdx.x == 0) {
    int run = 0;
    for (int b = 0; b < nb; b++) { int x = bsums[b]; bsums[b] = run; run += x; }
    *sentinel = run;
  }
}

__global__ void scan_add(int* __restrict__ out, const int* __restrict__ bsums, int n) {
  int base = blockIdx.x * 1024 + threadIdx.x * 4;
  int c = bsums[blockIdx.x];
#pragma unroll
  for (int j = 0; j < 4; j++) if (base + j < n) out[base + j] += c;
}

// ----------- one-time fold of edge attrs -> a_e for ALL layers, EDGE order.
// MFMA VERSION (r8 post-mortem: scalar form was issue-bound — 272 FMA + ~70
// ds_read per thread; occupancy-doubling changed nothing). The fold IS a GEMM
// [600K x 32] @ [32 x 17]: one wave = 16 edges, operand-swapped
// mfma_16x16x32_bf16 with hi/lo-split operands (3-term product, error ~2^-17
// — far below the existing bf16 xs/AS paths). cv folds in as the acc init.
struct FoldAeJobs {
  const float* ea[5];
};

__global__ __launch_bounds__(256) void fold_ae(FoldAeJobs J,
                                               const unsigned short* __restrict__ Wfh,
                                               const unsigned short* __restrict__ Wfl,
                                               const float* __restrict__ ccv,
                                               float* __restrict__ aet0, float* __restrict__ aet1,
                                               float* __restrict__ aet2) {
  int w = blockIdx.x * 4 + (threadIdx.x >> 6);   // wave id; 16 edges per wave
  int eg0 = w * 16;
  if (eg0 >= kETot) return;
  int t = 0;
  while (t < 4 && eg0 >= kEoff[t + 1]) t++;      // all relation sizes % 16 == 0
  int lane = threadIdx.x & 63;
  int l16 = lane & 15, quad = lane >> 4;
  int el = eg0 - kEoff[t] + l16;                 // this lane's edge row
  // load 8 fp32 of ea, split into bf16 hi + lo
  const float4* p4 = (const float4*)(J.ea[t] + (size_t)el * 32 + quad * 8);
  float4 a = p4[0], b = p4[1];
  float xv[8] = {a.x, a.y, a.z, a.w, b.x, b.y, b.z, b.w};
  unsigned hi[8], lo[8];
#pragma unroll
  for (int i = 0; i < 8; i++) {
    unsigned short h = f2b(xv[i]);
    hi[i] = h;
    lo[i] = f2b(xv[i] - b2f(h));
  }
  int4 hraw = make_int4((int)(hi[0] | (hi[1] << 16)), (int)(hi[2] | (hi[3] << 16)),
                        (int)(hi[4] | (hi[5] << 16)), (int)(hi[6] | (hi[7] << 16)));
  int4 lraw = make_int4((int)(lo[0] | (lo[1] << 16)), (int)(lo[2] | (lo[3] << 16)),
                        (int)(lo[4] | (lo[5] << 16)), (int)(lo[6] | (lo[7] << 16)));
  bf16x8 Ah = __builtin_bit_cast(bf16x8, hraw);
  bf16x8 Al = __builtin_bit_cast(bf16x8, lraw);
  // W fragments (L2-hot 20KB table): col = nt*16 + l16, k-chunk = quad
  size_t wb = (size_t)t * 1024 + (size_t)l16 * 32 + quad * 8;
  bf16x8 B0h = __builtin_bit_cast(bf16x8, *(const int4*)(Wfh + wb));
  bf16x8 B0l = __builtin_bit_cast(bf16x8, *(const int4*)(Wfl + wb));
  bf16x8 B1h = __builtin_bit_cast(bf16x8, *(const int4*)(Wfh + wb + 512));
  bf16x8 B1l = __builtin_bit_cast(bf16x8, *(const int4*)(Wfl + wb + 512));
  // acc init = cv constants per output column
  float4 c0 = *(const float4*)(ccv + t * 32 + quad * 4);
  float4 c1 = *(const float4*)(ccv + t * 32 + 16 + quad * 4);
  f32x4 acc0 = {c0.x, c0.y, c0.z, c0.w};
  f32x4 acc1 = {c1.x, c1.y, c1.z, c1.w};
  acc0 = __builtin_amdgcn_mfma_f32_16x16x32_bf16(B0h, Ah, acc0, 0, 0, 0);
  acc0 = __builtin_amdgcn_mfma_f32_16x16x32_bf16(B0l, Ah, acc0, 0, 0, 0);
  acc0 = __builtin_amdgcn_mfma_f32_16x16x32_bf16(B0h, Al, acc0, 0, 0, 0);
  acc1 = __builtin_amdgcn_mfma_f32_16x16x32_bf16(B1h, Ah, acc1, 0, 0, 0);
  acc1 = __builtin_amdgcn_mfma_f32_16x16x32_bf16(B1l, Ah, acc1, 0, 0, 0);
  acc1 = __builtin_amdgcn_mfma_f32_16x16x32_bf16(B1h, Al, acc1, 0, 0, 0);
  // thread (l16,quad) holds cols quad*4..+3 (nt=0) / 16+quad*4..+3 (nt=1)
  // of edge eg0+l16. cols 0-7 -> aet0, 8-15 -> aet1, 16 -> aet2.
  int eg = eg0 + l16;
  float4 o = make_float4(acc0[0], acc0[1], acc0[2], acc0[3]);
  if (quad == 0)      *(float4*)(aet0 + (size_t)eg * 8)     = o;
  else if (quad == 1) *(float4*)(aet0 + (size_t)eg * 8 + 4) = o;
  else if (quad == 2) *(float4*)(aet1 + (size_t)eg * 8)     = o;
  else                *(float4*)(aet1 + (size_t)eg * 8 + 4) = o;
  if (quad == 0) aet2[eg] = acc1[0];
}

// ------------- per-layer logit pass, streaming in CSR order.
__global__ __launch_bounds__(256) void pass_a8(const int4* __restrict__ edat,
                                               const float* __restrict__ aet,
                                               const float* __restrict__ AS,
                                               float* __restrict__ logits) {
  int p = blockIdx.x * 256 + threadIdx.x;
  if (p >= kETot) return;
  int4 ed = edat[p];
  int e = ed.x, sv = ed.y, dv = ed.z;
  int t = sv & 7;
  const float4* asp = (const float4*)(AS + (size_t)(sv >> 3) * 80 + t * 8);
  const float4* adp = (const float4*)(AS + (size_t)(dv >> 3) * 80 + (5 + t) * 8);
  const float4* aep = (const float4*)(aet + (size_t)e * 8);
  float4 s0 = asp[0], s1 = asp[1];
  float4 d0 = adp[0], d1 = adp[1];
  float4 e0 = aep[0], e1 = aep[1];
  float v[8] = {s0.x + d0.x + e0.x, s0.y + d0.y + e0.y, s0.z + d0.z + e0.z, s0.w + d0.w + e0.w,
                s1.x + d1.x + e1.x, s1.y + d1.y + e1.y, s1.z + d1.z + e1.z, s1.w + d1.w + e1.w};
#pragma unroll
  for (int j = 0; j < 8; j++) v[j] = v[j] > 0.f ? v[j] : 0.2f * v[j];
  float4* L = (float4*)(logits + (size_t)p * 8);
  L[0] = make_float4(v[0], v[1], v[2], v[3]);
  L[1] = make_float4(v[4], v[5], v[6], v[7]);
}

__global__ __launch_bounds__(256) void pass_a1(const int4* __restrict__ edat,
                                               const float* __restrict__ aet2,
                                               const float* __restrict__ AS,
                                               float* __restrict__ logits) {
  int p = blockIdx.x * 256 + threadIdx.x;
  if (p >= kETot) return;
  int4 ed = edat[p];
  int e = ed.x, sv = ed.y, dv = ed.z;
  int t = sv & 7;
  float v = aet2[e] + AS[(size_t)(sv >> 3) * 16 + t] + AS[(size_t)(dv >> 3) * 16 + 5 + t];
  v = v > 0.f ? v : 0.2f * v;
  logits[p] = v;
}

// ------- segment softmax per (dst,relation) sub-segment, in place -> alpha
// Register-resident fast path (n<=256, >99% of segments): ONE read pass into
// registers + ONE write pass, vs 3 dependent global round-trips.
template <int H>
__global__ void softmax_k(const int* __restrict__ rs, float* __restrict__ lg) {
  int g = (int)((blockIdx.x * (size_t)blockDim.x + threadIdx.x) >> 6);
  int lane = threadIdx.x & 63;
  if (g >= kSeg) return;
  int start = rs[g], end = rs[g + 1];
  int n = (end - start) * H;
  if (n == 0) return;
  float* L = lg + (size_t)start * H;
  if (n <= 256) {
    float v[4];
#pragma unroll
    for (int j = 0; j < 4; j++) {
      int idx = lane + 64 * j;
      v[j] = (idx < n) ? L[idx] : -3.0e38f;
    }
    float m = fmaxf(fmaxf(v[0], v[1]), fmaxf(v[2], v[3]));
    if (H == 8) {
      m = fmaxf(m, __shfl_xor(m, 8));
      m = fmaxf(m, __shfl_xor(m, 16));
      m = fmaxf(m, __shfl_xor(m, 32));
    } else {
#pragma unroll
      for (int off = 1; off < 64; off <<= 1) m = fmaxf(m, __shfl_xor(m, off));
    }
    float s = 0.f;
#pragma unroll
    for (int j = 0; j < 4; j++) {
      v[j] = __expf(v[j] - m);   // masked lanes: exp(-huge) = 0
      s += v[j];
    }
    if (H == 8) {
      s += __shfl_xor(s, 8);
      s += __shfl_xor(s, 16);
      s += __shfl_xor(s, 32);
    } else {
#pragma unroll
      for (int off = 1; off < 64; off <<= 1) s += __shfl_xor(s, off);
    }
    float inv = 1.f / (s + 1e-16f);
#pragma unroll
    for (int j = 0; j < 4; j++) {
      int idx = lane + 64 * j;
      if (idx < n) L[idx] = v[j] * inv;
    }
    return;
  }
  // fallback (large machine segments at H=8): original 3-pass loop
  float m = -3.0e38f;
  for (int idx = lane; idx < n; idx += 64) m = fmaxf(m, L[idx]);
  if (H == 8) {
    m = fmaxf(m, __shfl_xor(m, 8));
    m = fmaxf(m, __shfl_xor(m, 16));
    m = fmaxf(m, __shfl_xor(m, 32));
  } else {
#pragma unroll
    for (int off = 1; off < 64; off <<= 1) m = fmaxf(m, __shfl_xor(m, off));
  }
  float s = 0.f;
  for (int idx = lane; idx < n; idx += 64) {
    float ex = __expf(L[idx] - m);
    L[idx] = ex;
    s += ex;
  }
  if (H == 8) {
    s += __shfl_xor(s, 8);
    s += __shfl_xor(s, 16);
    s += __shfl_xor(s, 32);
  } else {
#pragma unroll
    for (int off = 1; off < 64; off <<= 1) s += __shfl_xor(s, off);
  }
  float inv = 1.f / (s + 1e-16f);
  for (int idx = lane; idx < n; idx += 64) L[idx] *= inv;
}

// --------------- unified gather: agg[g] = sum over node's sub-segments of alpha*xs
template <int H>
__global__ void gat_gather_u(const int* __restrict__ rs, const int4* __restrict__ edat,
                             const float* __restrict__ alpha,
                             const unsigned short* __restrict__ xs,
                             float* __restrict__ agg) {
  int g = (int)((blockIdx.x * (size_t)blockDim.x + threadIdx.x) >> 6);
  int lane = threadIdx.x & 63;
  if (g >= kNTot) return;
  int start, end;
  if (g < 50000)      { start = rs[3 * g];              end = rs[3 * g + 3]; }
  else if (g < 51000) { int m = g - 50000; start = rs[150000 + m]; end = rs[150001 + m]; }
  else                { int j = g - 51000; start = rs[151000 + j]; end = rs[151001 + j]; }
  int deg = end - start;
  int l16 = lane & 15, quad = lane >> 4;
  int h = (H == 8) ? (l16 >> 1) : 0;
  float acc[8] = {0.f, 0.f, 0.f, 0.f, 0.f, 0.f, 0.f, 0.f};
  for (int base = 0; base < deg; base += 64) {
    int nchunk = deg - base; if (nchunk > 64) nchunk = 64;
    int sv = (lane < nchunk) ? edat[start + base + lane].w : 0;
    for (int i = 0; i < nchunk; i += 4) {
      int e = i + quad;
      bool act = e < nchunk;
      int s = __shfl(sv, act ? e : 0);
      float w = act ? alpha[(size_t)(start + base + e) * H + h] : 0.f;
      int4 raw = *(const int4*)(xs + (size_t)s * HID + l16 * 8);
      unsigned ua[4] = {(unsigned)raw.x, (unsigned)raw.y, (unsigned)raw.z, (unsigned)raw.w};
#pragma unroll
      for (int j = 0; j < 4; j++) {
        acc[2 * j]     += w * __uint_as_float(ua[j] << 16);
        acc[2 * j + 1] += w * __uint_as_float(ua[j] & 0xFFFF0000u);
      }
    }
  }
#pragma unroll
  for (int j = 0; j < 8; j++) {
    acc[j] += __shfl_xor(acc[j], 16);
    acc[j] += __shfl_xor(acc[j], 32);
  }
  if (quad == 0) {
    float* p = agg + (size_t)g * HID + l16 * 8;
    *(float4*)p = make_float4(acc[0], acc[1], acc[2], acc[3]);
    *(float4*)(p + 4) = make_float4(acc[4], acc[5], acc[6], acc[7]);
  }
}

// ------------------------------------------------- BatchNorm column stats
__global__ void colstats_b(const float* __restrict__ x, float* __restrict__ stats) {
  static constexpr int bpref[4] = {0, 384, 400, 448};
  static constexpr int rowoff[4] = {0, 50000, 51000, 56000};
  int b = blockIdx.x;
  int t = 0;
  while (t < 2 && b >= bpref[t + 1]) t++;
  int bl = b - bpref[t], nb = bpref[t + 1] - bpref[t];
  int tid = threadIdx.x;
  int col = tid & 127, half = tid >> 7;
  float s = 0.f, q = 0.f;
  for (int r = rowoff[t] + bl * 2 + half; r < rowoff[t + 1]; r += nb * 2) {
    float v = x[(size_t)r * HID + col];
    s += v; q += v * v;
  }
  __shared__ float ls[256], lq[256];
  ls[tid] = s; lq[tid] = q;
  __syncthreads();
  if (tid < 128) {
    s = ls[tid] + ls[tid + 128];
    q = lq[tid] + lq[tid + 128];
    unsafeAtomicAdd(&stats[t * 256 + col], s);
    unsafeAtomicAdd(&stats[t * 256 + 128 + col], q);
  }
}

// --- BN apply + ReLU + residual: fp32 agg (in-place -> new x) + bf16 shadow
__global__ void bn_apply_b(float* __restrict__ agg, const float* __restrict__ xold,
                           unsigned short* __restrict__ xnb, const float* __restrict__ stats,
                           const float* __restrict__ gammaL, const float* __restrict__ betaL,
                           int relu) {
  size_t i = blockIdx.x * (size_t)blockDim.x + threadIdx.x;
  if (i >= (size_t)kNTot * 32) return;
  int row = (int)(i >> 5);
  int t = (row < 50000) ? 0 : (row < 51000 ? 1 : 2);
  float invN = (t == 0) ? (1.f / 50000.f) : (t == 1 ? (1.f / 1000.f) : (1.f / 5000.f));
  const float* st = stats + t * 256;
  const float* gm = gammaL + t * HID;
  const float* bt = betaL + t * HID;
  int c4 = ((int)(i & 31)) * 4;
  float4 av = ((const float4*)agg)[i];
  float4 xv = ((const float4*)xold)[i];
  float a[4] = {av.x, av.y, av.z, av.w};
  float xo[4] = {xv.x, xv.y, xv.z, xv.w};
  float o[4];
#pragma unroll
  for (int j = 0; j < 4; j++) {
    int c = c4 + j;
    float mu = st[c] * invN;
    float var = st[128 + c] * invN - mu * mu;
    float g = gm[c] * rsqrtf(var + 1e-5f);
    float v = (a[j] - mu) * g + bt[c];
    if (relu) v = fmaxf(v, 0.f);
    o[j] = v + xo[j];
  }
  ((float4*)agg)[i] = make_float4(o[0], o[1], o[2], o[3]);
  ((ushort4*)xnb)[i] = make_ushort4(f2b(o[0]), f2b(o[1]), f2b(o[2]), f2b(o[3]));
}

// ============================================================== host driver
extern "C" void kernel_launch(void* const* d_in, const int* in_sizes, int n_in,
                              void* d_out, int out_size, void* d_ws, size_t ws_size,
                              hipStream_t stream) {
  const float* x_in[3] = {(const float*)d_in[0], (const float*)d_in[1], (const float*)d_in[2]};
  const int* ei[5];
  const float* ea[5];
  for (int t = 0; t < 5; t++) {
    ei[t] = (const int*)d_in[3 + 2 * t];
    ea[t] = (const float*)d_in[4 + 2 * t];
  }
  const float* Wn[3]  = {(const float*)d_in[13], (const float*)d_in[15], (const float*)d_in[17]};
  const float* bnb[3] = {(const float*)d_in[14], (const float*)d_in[16], (const float*)d_in[18]};
  const float* Wep   = (const float*)d_in[19];
  const float* bep   = (const float*)d_in[20];
  const float* Wg    = (const float*)d_in[21];
  const float* att_s = (const float*)d_in[22];
  const float* att_d = (const float*)d_in[23];
  const float* Wge   = (const float*)d_in[24];
  const float* att_e = (const float*)d_in[25];
  // d_in[26] = bg: cancelled exactly by BatchNorm mean-subtraction; unused.
  const float* gamma = (const float*)d_in[27];
  const float* beta  = (const float*)d_in[28];
  const float* Wo    = (const float*)d_in[29];
  const float* bo    = (const float*)d_in[30];

  float* ws = (float*)d_ws;
  size_t off = 0;
  auto alloc = [&](size_t n) { size_t o = off; off += (n + 255) & ~(size_t)255; return o; };
  auto allocb = [&](size_t n) { return alloc((n + 1) / 2); };

  float* bufA = ws + alloc((size_t)kNTot * HID);   // fp32 x (residual chain)
  float* bufB = ws + alloc((size_t)kNTot * HID);   // fp32 agg / next x
  unsigned short* xcurb = (unsigned short*)(ws + allocb((size_t)kNTot * HID));
  unsigned short* xs_all = (unsigned short*)(ws + allocb((size_t)kRTot * HID));
  unsigned short* WgT  = (unsigned short*)(ws + allocb((size_t)15 * HID * HID));
  unsigned short* WoT  = (unsigned short*)(ws + allocb((size_t)HID * HID));
  unsigned short* WnT_op  = (unsigned short*)(ws + allocb((size_t)HID * 64));
  unsigned short* WnT_ma  = (unsigned short*)(ws + allocb((size_t)HID * 32));
  unsigned short* WnT_job = (unsigned short*)(ws + allocb((size_t)HID * 32));
  unsigned short* VbT  = (unsigned short*)(ws + allocb((size_t)3 * 80 * HID));
  unsigned short* Wfh  = (unsigned short*)(ws + allocb((size_t)5 * 32 * 32));
  unsigned short* Wfl  = (unsigned short*)(ws + allocb((size_t)5 * 32 * 32));
  float* ccv    = ws + alloc((size_t)5 * 32);
  float* Sv     = ws + alloc((size_t)15 * 8 * HID);
  float* Dv     = ws + alloc((size_t)15 * 8 * HID);
  float* w32    = ws + alloc((size_t)15 * 8 * 32);
  float* cv     = ws + alloc((size_t)15 * 8);
  float* stats  = ws + alloc((size_t)3 * 256);
  float* ASbuf  = ws + alloc((size_t)kNTot * 80);
  float* logits = ws + alloc((size_t)kETot * 8 + 64);
  int* rs_all   = (int*)(ws + alloc((size_t)kSeg + 8));
  int4* edat    = (int4*)(ws + alloc((size_t)kETot * 4));  // {e, spack, dpack, ssrc}
  float* aet0   = ws + alloc((size_t)kETot * 8);   // edge-order a_e, layer 0 (H=8)
  float* aet1   = ws + alloc((size_t)kETot * 8);   // layer 1 (H=8)
  float* aet2   = ws + alloc((size_t)kETot);       // layer 2 (H=1)
  // aliases: xinb_* live inside xs_all (consumed before xs_all is written);
  // cnt/rank/bsums live inside logits (CSR build precedes first logit write)
  unsigned short* xinb_op  = xs_all;                          // 3.2M ushorts
  unsigned short* xinb_ma  = xs_all + 3200000;                // 32k ushorts
  unsigned short* xinb_job = xs_all + 3232000;                // 160k ushorts
  int* cnt    = (int*)logits;                       // 156,032 ints
  int* rank   = (int*)(logits + 156032);            // 600,000 ints
  int* bsums  = (int*)(logits + 756288);            // 160 ints
  (void)ws_size; (void)in_sizes; (void)n_in; (void)out_size;

  float* xcur = bufA;
  float* agg  = bufB;

  // -------- unified CSR over (dst,relation) sub-segments, built once
  EdgeJobs EJ;
  for (int t = 0; t < 5; t++) { EJ.src[t] = ei[t]; EJ.dst[t] = ei[t] + kEsz[t]; }
  hipMemsetAsync(cnt, 0, (size_t)kSeg * 4, stream);
  hist_rank<<<(kETot + 255) / 256, 256, 0, stream>>>(EJ, cnt, rank);
  int nb = (kSeg + 1023) / 1024;
  scan_blocks<<<nb, 256, 0, stream>>>(cnt, rs_all, bsums, kSeg);
  scan_carry<<<1, 64, 0, stream>>>(bsums, nb, rs_all + kSeg);
  scan_add<<<nb, 256, 0, stream>>>(rs_all, bsums, kSeg);
  scatter_b<<<(kETot + 255) / 256, 256, 0, stream>>>(EJ, rs_all, rank, edat);

  // -------- bf16 conversions
  conv_pad<<<(kNOp * 64 + 255) / 256, 256, 0, stream>>>(x_in[0], xinb_op, kNOp, 64, 64);
  conv_pad<<<(kNMa * 32 + 255) / 256, 256, 0, stream>>>(x_in[1], xinb_ma, kNMa, 32, 32);
  conv_pad<<<(kNJob * 32 + 255) / 256, 256, 0, stream>>>(x_in[2], xinb_job, kNJob, 16, 32);
  transpose_w<<<(HID * 64 + 255) / 256, 256, 0, stream>>>(Wn[0], WnT_op, 64, HID, 64, 1);
  transpose_w<<<(HID * 32 + 255) / 256, 256, 0, stream>>>(Wn[1], WnT_ma, 32, HID, 32, 1);
  transpose_w<<<(HID * 32 + 255) / 256, 256, 0, stream>>>(Wn[2], WnT_job, 16, HID, 32, 1);
  transpose_w<<<(15 * HID * HID + 255) / 256, 256, 0, stream>>>(Wg, WgT, HID, HID, HID, 15);
  transpose_w<<<(HID * HID + 255) / 256, 256, 0, stream>>>(Wo, WoT, HID, HID, HID, 1);
  fold_kernel<<<120, 128, 0, stream>>>(Wg, att_s, att_d, Wge, att_e, Wep, bep,
                                       Sv, Dv, w32, cv);
  build_vb<<<(3 * 80 * HID + 255) / 256, 256, 0, stream>>>(Sv, Dv, VbT);
  build_wf<<<(5 * 32 * 32 + 255) / 256, 256, 0, stream>>>(w32, cv, Wfh, Wfl, ccv);

  // -------- one-time edge-attr fold for all 3 layers (MFMA, hi/lo split)
  FoldAeJobs FJ;
  for (int t = 0; t < 5; t++) FJ.ea[t] = ea[t];
  fold_ae<<<kETot / 64, 256, 0, stream>>>(FJ, Wfh, Wfl, ccv, aet0, aet1, aet2);

  // -------- node input projections (fp32 x + bf16 shadow)
  gemm_mfma<2><<<((kNOp + 15) / 16 + 3) / 4, 256, 0, stream>>>(
      xinb_op, WnT_op, bnb[0], xcur, xcurb, kNOp);
  gemm_mfma<1><<<((kNMa + 15) / 16 + 3) / 4, 256, 0, stream>>>(
      xinb_ma, WnT_ma, bnb[1], xcur + (size_t)50000 * HID, xcurb + (size_t)50000 * HID, kNMa);
  gemm_mfma<1><<<((kNJob + 15) / 16 + 3) / 4, 256, 0, stream>>>(
      xinb_job, WnT_job, bnb[2], xcur + (size_t)51000 * HID, xcurb + (size_t)51000 * HID, kNJob);

  for (int l = 0; l < 3; l++) {
    int H = (l < 2) ? 8 : 1;

    // xs for all 5 relations; LDS-staged weights, LDS-bounced coalesced stores
    gemm_xs<<<877, 256, 0, stream>>>(xcurb, WgT + (size_t)l * 5 * HID * HID, xs_all);

    // a_s/a_d for all (relation, head) via one MFMA GEMM
    int asBlocks = ((kNTot + 15) / 16 + 3) / 4;
    if (H == 8)
      gemm_as<80><<<asBlocks, 256, 0, stream>>>(xcurb, VbT + (size_t)l * 80 * HID, ASbuf, kNTot);
    else
      gemm_as<16><<<asBlocks, 256, 0, stream>>>(xcurb, VbT + (size_t)l * 80 * HID, ASbuf, kNTot);

    // logits: streaming pass over CSR-ordered edges (aet gathered via edat.x)
    int pblocks = (kETot + 255) / 256;
    if (H == 8) {
      const float* aeL = (l == 0) ? aet0 : aet1;
      pass_a8<<<pblocks, 256, 0, stream>>>(edat, aeL, ASbuf, logits);
    } else {
      pass_a1<<<pblocks, 256, 0, stream>>>(edat, aet2, ASbuf, logits);
    }

    if (H == 8) {
      softmax_k<8><<<((size_t)kSeg * 64 + 255) / 256, 256, 0, stream>>>(rs_all, logits);
      gat_gather_u<8><<<((size_t)kNTot * 64 + 255) / 256, 256, 0, stream>>>(
          rs_all, edat, logits, xs_all, agg);
    } else {
      softmax_k<1><<<((size_t)kSeg * 64 + 255) / 256, 256, 0, stream>>>(rs_all, logits);
      gat_gather_u<1><<<((size_t)kNTot * 64 + 255) / 256, 256, 0, stream>>>(
          rs_all, edat, logits, xs_all, agg);
    }

    hipMemsetAsync(stats, 0, 3 * 256 * 4, stream);
    colstats_b<<<448, 256, 0, stream>>>(agg, stats);
    bn_apply_b<<<(unsigned)(((size_t)kNTot * 32 + 255) / 256), 256, 0, stream>>>(
        agg, xcur, xcurb, stats, gamma + (size_t)l * 3 * HID, beta + (size_t)l * 3 * HID,
        (l < 2) ? 1 : 0);
    float* tmp = xcur; xcur = agg; agg = tmp;   // agg now holds new fp32 x
  }

  gemm_mfma<4><<<((kNOp + 15) / 16 + 3) / 4, 256, 0, stream>>>(
      xcurb, WoT, bo, (float*)d_out, nullptr, kNOp);
}

// Round 10
// 842.492 us; speedup vs baseline: 1.0168x; 1.0168x over previous
//
#include <hip/hip_runtime.h>
#include <cstdint>

#define HID 128

static constexpr int kNOp = 50000, kNMa = 1000, kNJob = 5000;
static constexpr int kNTot = 56000;                 // op | ma | job global node space
static constexpr int kETot = 600000;
static constexpr int kSeg = 156000;                 // (dst,relation) sub-segments
static constexpr int kEsz[5]   = {150000, 100000, 150000, 100000, 100000};
static constexpr int kSrcT[5]  = {0, 0, 1, 2, 0};
static constexpr int kDstT[5]  = {0, 1, 0, 0, 2};
static constexpr int kNodeOff[3] = {0, 50000, 51000};
static constexpr int kSoff[5]  = {0, 0, 50000, 51000, 0};
static constexpr int kDoff[5]  = {0, 50000, 0, 0, 51000};
static constexpr int kEoff[6]  = {0, 150000, 250000, 400000, 500000, 600000};
static constexpr int kRoff[5]  = {0, 50000, 100000, 101000, 106000};  // xs_all row offset (src counts)
static constexpr int kRTot = 156000;

typedef __attribute__((ext_vector_type(8))) __bf16 bf16x8;
typedef __attribute__((ext_vector_type(4))) float f32x4;

__device__ inline unsigned short f2b(float f) {
  unsigned u = __float_as_uint(f);
  unsigned r = (u + 0x7FFFu + ((u >> 16) & 1u)) >> 16;
  return (unsigned short)r;
}
__device__ inline float b2f(unsigned short u) {
  return __uint_as_float(((unsigned)u) << 16);
}

// (dst,relation) -> softmax sub-segment id; op sub-segments contiguous per node
__device__ inline int seg_of(int t, int d) {
  if (t == 0) return 3 * d;
  if (t == 2) return 3 * d + 1;
  if (t == 3) return 3 * d + 2;
  if (t == 1) return 150000 + d;
  return 151000 + d;  // t4
}

// ------------------------------------------------ fp32 -> bf16 (pad K to Kp)
__global__ void conv_pad(const float* __restrict__ in, unsigned short* __restrict__ out,
                         int M, int K, int Kp) {
  int i = blockIdx.x * blockDim.x + threadIdx.x;
  if (i >= M * Kp) return;
  int r = i / Kp, c = i - r * Kp;
  out[i] = (c < K) ? f2b(in[(size_t)r * K + c]) : (unsigned short)0;
}

// ---------------------- W[K x N] fp32 -> Wt[N x Kp] bf16 (batched, zero-pad K)
__global__ void transpose_w(const float* __restrict__ W, unsigned short* __restrict__ Wt,
                            int K, int N, int Kp, int nmat) {
  int i = blockIdx.x * blockDim.x + threadIdx.x;
  int per = N * Kp;
  if (i >= nmat * per) return;
  int b = i / per, rem = i - b * per;
  int n = rem / Kp, k = rem - n * Kp;
  Wt[i] = (k < K) ? f2b(W[(size_t)b * K * N + (size_t)k * N + n]) : (unsigned short)0;
}

// --------------------------------------------- plain bf16 MFMA GEMM (N=128)
// OPERAND-SWAPPED: acc = mfma(W_frag, x_frag) -> D[wcol][xrow]; each thread
// holds 4 CONSECUTIVE output cols of one x-row -> float4/ushort4 stores.
template <int KC>   // K = KC*32
__global__ __launch_bounds__(256) void gemm_mfma(
    const unsigned short* __restrict__ A, const unsigned short* __restrict__ Bt,
    const float* __restrict__ bias, float* __restrict__ Cf,
    unsigned short* __restrict__ Cb, int M) {
  const int K = KC * 32;
  int w = blockIdx.x * 4 + (threadIdx.x >> 6);
  int m0 = w * 16;
  if (m0 >= M) return;
  int lane = threadIdx.x & 63;
  int l16 = lane & 15, quad = lane >> 4;
  int xrow = m0 + l16; if (xrow >= M) xrow = M - 1;
  bf16x8 xf[KC];
#pragma unroll
  for (int kc = 0; kc < KC; kc++) {
    int4 raw = *(const int4*)(A + (size_t)xrow * K + kc * 32 + quad * 8);
    xf[kc] = __builtin_bit_cast(bf16x8, raw);
  }
  bool wr = (m0 + l16 < M);
  int row = m0 + l16;
#pragma unroll
  for (int nt = 0; nt < 8; nt++) {
    f32x4 acc = {0.f, 0.f, 0.f, 0.f};
#pragma unroll
    for (int kc = 0; kc < KC; kc++) {
      int4 braw = *(const int4*)(Bt + (size_t)(nt * 16 + l16) * K + kc * 32 + quad * 8);
      acc = __builtin_amdgcn_mfma_f32_16x16x32_bf16(
          __builtin_bit_cast(bf16x8, braw), xf[kc], acc, 0, 0, 0);
    }
    int col0 = nt * 16 + quad * 4;
    float o[4];
#pragma unroll
    for (int r = 0; r < 4; r++) o[r] = acc[r] + (bias ? bias[col0 + r] : 0.f);
    if (wr) {
      if (Cf) *(float4*)(Cf + (size_t)row * HID + col0) = make_float4(o[0], o[1], o[2], o[3]);
      if (Cb) *(ushort4*)(Cb + (size_t)row * HID + col0) =
                  make_ushort4(f2b(o[0]), f2b(o[1]), f2b(o[2]), f2b(o[3]));
    }
  }
}

// ------------- fused xs GEMM with LDS-staged weights + LDS-bounced stores.
// Block = 64 rows (4 waves x 16). Per relation: Wg[t] (32KB) staged ONCE per
// block into LDS; out tiles bounced through LDS -> 4 x 1KB coalesced stores.
__global__ __launch_bounds__(256) void gemm_xs(const unsigned short* __restrict__ x,
                                               const unsigned short* __restrict__ WgTl,
                                               unsigned short* __restrict__ xs) {
  __shared__ __align__(16) unsigned short Bs[128 * 136];    // +16B row pad (bank)
  __shared__ __align__(16) unsigned short Os[4][16 * 136];
  // blocks [0,782): op; [782,798): ma; [798,877): job  (64 rows per block)
  int b = blockIdx.x;
  int grp = (b < 782) ? 0 : (b < 798 ? 1 : 2);
  int sb   = (grp == 0) ? 0     : (grp == 1 ? 782   : 798);
  int M    = (grp == 0) ? 50000 : (grp == 1 ? 1000  : 5000);
  int xoff = (grp == 0) ? 0     : (grp == 1 ? 50000 : 51000);
  int tid = threadIdx.x;
  int wid = tid >> 6, lane = tid & 63;
  int l16 = lane & 15, quad = lane >> 4;
  int m0 = (b - sb) * 64 + wid * 16;
  int xrow = m0 + l16; if (xrow >= M) xrow = M - 1;
  bf16x8 xf[4];
#pragma unroll
  for (int kc = 0; kc < 4; kc++) {
    int4 raw = *(const int4*)(x + (size_t)(xoff + xrow) * HID + kc * 32 + quad * 8);
    xf[kc] = __builtin_bit_cast(bf16x8, raw);
  }
  int nrel = (grp == 0) ? 3 : 1;
  int rel0  = (grp == 0) ? 0 : (grp == 1 ? 2 : 3);
  int roff0 = (grp == 0) ? 0 : (grp == 1 ? 100000 : 101000);
  int rels[3]  = {rel0, 1, 4};
  int roffs[3] = {roff0, 50000, 106000};
  for (int rr = 0; rr < nrel; rr++) {
    int t = rels[rr];
    unsigned short* Cb = xs + (size_t)roffs[rr] * HID;
    __syncthreads();   // all waves done reading previous Bs
    const unsigned short* Wsrc = WgTl + (size_t)t * HID * HID;
    for (int c = tid; c < 2048; c += 256) {       // 2048 x int4 = 32KB, coalesced
      int row = c >> 4, k8 = c & 15;
      *(int4*)&Bs[row * 136 + k8 * 8] = *(const int4*)(Wsrc + row * 128 + k8 * 8);
    }
    __syncthreads();
#pragma unroll
    for (int nt = 0; nt < 8; nt++) {
      f32x4 acc = {0.f, 0.f, 0.f, 0.f};
#pragma unroll
      for (int kc = 0; kc < 4; kc++) {
        bf16x8 bfr = *(const bf16x8*)&Bs[(nt * 16 + l16) * 136 + kc * 32 + quad * 8];
        acc = __builtin_amdgcn_mfma_f32_16x16x32_bf16(bfr, xf[kc], acc, 0, 0, 0);
      }
      *(ushort4*)&Os[wid][l16 * 136 + nt * 16 + quad * 4] =
          make_ushort4(f2b(acc[0]), f2b(acc[1]), f2b(acc[2]), f2b(acc[3]));
    }
    // wave-private tile -> global, 4 x 1KB contiguous store instructions
#pragma unroll
    for (int i = 0; i < 4; i++) {
      int g = i * 1024 + lane * 16;     // byte offset within the 4KB tile
      int row = g >> 8;
      int colb = g & 255;
      int4 v = *(const int4*)((const char*)&Os[wid][0] + row * 272 + colb);
      if (m0 + row < M)
        *(int4*)((char*)(Cb + (size_t)(m0 + row) * HID) + colb) = v;
    }
  }
}

// ---------------- AS GEMM: AS[M x NCOL] = x[M x 128] @ VbT^T, fp32 out
// (operand-swapped -> float4 coalesced stores)
template <int NCOL>
__global__ __launch_bounds__(256) void gemm_as(
    const unsigned short* __restrict__ A, const unsigned short* __restrict__ Bt,
    float* __restrict__ out, int M) {
  int w = blockIdx.x * 4 + (threadIdx.x >> 6);
  int m0 = w * 16;
  if (m0 >= M) return;
  int lane = threadIdx.x & 63;
  int l16 = lane & 15, quad = lane >> 4;
  int xrow = m0 + l16; if (xrow >= M) xrow = M - 1;
  bf16x8 xf[4];
#pragma unroll
  for (int kc = 0; kc < 4; kc++) {
    int4 raw = *(const int4*)(A + (size_t)xrow * HID + kc * 32 + quad * 8);
    xf[kc] = __builtin_bit_cast(bf16x8, raw);
  }
  bool wr = (m0 + l16 < M);
  int row = m0 + l16;
#pragma unroll
  for (int nt = 0; nt < NCOL / 16; nt++) {
    f32x4 acc = {0.f, 0.f, 0.f, 0.f};
#pragma unroll
    for (int kc = 0; kc < 4; kc++) {
      int4 braw = *(const int4*)(Bt + (size_t)(nt * 16 + l16) * HID + kc * 32 + quad * 8);
      acc = __builtin_amdgcn_mfma_f32_16x16x32_bf16(
          __builtin_bit_cast(bf16x8, braw), xf[kc], acc, 0, 0, 0);
    }
    if (wr) {
      int col0 = nt * 16 + quad * 4;
      *(float4*)(out + (size_t)row * NCOL + col0) = make_float4(acc[0], acc[1], acc[2], acc[3]);
    }
  }
}

// ------------------------------------------------- fold attention vectors
// S[lt,h,k] = sum_c Wg[k][hC+c]*att_s[hC+c]; D likewise; w32/cvec edge fold.
__global__ void fold_kernel(const float* __restrict__ Wg, const float* __restrict__ att_s,
                            const float* __restrict__ att_d, const float* __restrict__ Wge,
                            const float* __restrict__ att_e, const float* __restrict__ Wep,
                            const float* __restrict__ bep,
                            float* __restrict__ S, float* __restrict__ D,
                            float* __restrict__ w32, float* __restrict__ cvec) {
  int idx = blockIdx.x;          // (l*5+t)*8 + h
  int h = idx & 7, lt = idx >> 3;
  int l = lt / 5;
  int H = (l < 2) ? 8 : 1, C = HID / H;
  if (h >= H) return;
  int k = threadIdx.x;           // 0..127
  int t = lt % 5;
  const float* wg  = Wg  + (size_t)lt * HID * HID;
  const float* wge = Wge + (size_t)lt * HID * HID;
  const float* as_ = att_s + (size_t)lt * HID + h * C;
  const float* ad_ = att_d + (size_t)lt * HID + h * C;
  const float* ae_ = att_e + (size_t)lt * HID + h * C;
  float s = 0.f, d = 0.f, v = 0.f;
  for (int c = 0; c < C; c++) {
    float wr = wg[(size_t)k * HID + h * C + c];
    s += wr * as_[c];
    d += wr * ad_[c];
    v += wge[(size_t)k * HID + h * C + c] * ae_[c];
  }
  S[(size_t)idx * HID + k] = s;
  D[(size_t)idx * HID + k] = d;
  __shared__ float vs[HID];
  vs[k] = v;
  __syncthreads();
  if (k < 32) {
    const float* wp = Wep + (size_t)t * 32 * HID + (size_t)k * HID;
    float a = 0.f;
    for (int j = 0; j < HID; j++) a += wp[j] * vs[j];
    w32[(size_t)idx * 32 + k] = a;
  }
  if (k == 32) {
    const float* bp = bep + (size_t)t * HID;
    float a = 0.f;
    for (int j = 0; j < HID; j++) a += bp[j] * vs[j];
    cvec[idx] = a;
  }
}

// ------ pack folded S/D vectors into bf16 Bt layout: VbT[l][col][k], col=(v,h)
// v in 0..9: v<5 -> S of relation v; v>=5 -> D of relation v-5. 80 cols/layer.
__global__ void build_vb(const float* __restrict__ Sv, const float* __restrict__ Dv,
                         unsigned short* __restrict__ VbT) {
  int i = blockIdx.x * 256 + threadIdx.x;
  if (i >= 3 * 80 * HID) return;
  int l = i / (80 * HID), rem = i % (80 * HID);
  int col = rem / HID, k = rem % HID;
  int H = (l < 2) ? 8 : 1;
  float val = 0.f;
  if (col < 10 * H) {
    int v = col / H, h = col % H;
    const float* base = (v < 5) ? Sv : Dv;
    int t = (v < 5) ? v : v - 5;
    val = base[((size_t)(l * 5 + t) * 8 + h) * HID + k];
  }
  VbT[i] = f2b(val);
}

// ---- build the fold-GEMM B matrix: Wf[t][col 0..31][k 0..31] bf16 hi/lo.
// col 0-7 = layer0 heads, 8-15 = layer1 heads, 16 = layer2, 17-31 = zero.
__global__ void build_wf(const float* __restrict__ w32, const float* __restrict__ cv,
                         unsigned short* __restrict__ Wfh, unsigned short* __restrict__ Wfl,
                         float* __restrict__ ccv) {
  int i = blockIdx.x * 256 + threadIdx.x;
  if (i >= 5 * 32 * 32) return;
  int t = i >> 10, rem = i & 1023;
  int col = rem >> 5, k = rem & 31;
  float val = 0.f, c = 0.f;
  if (col < 8)        { val = w32[((size_t)((0 * 5 + t) * 8 + col)) * 32 + k];       c = cv[(0 * 5 + t) * 8 + col]; }
  else if (col < 16)  { val = w32[((size_t)((1 * 5 + t) * 8 + (col - 8))) * 32 + k]; c = cv[(1 * 5 + t) * 8 + col - 8]; }
  else if (col == 16) { val = w32[((size_t)((2 * 5 + t) * 8 + 0)) * 32 + k];         c = cv[(2 * 5 + t) * 8]; }
  unsigned short h = f2b(val);
  Wfh[i] = h;
  Wfl[i] = f2b(val - b2f(h));
  if (k == 0) ccv[t * 32 + col] = c;
}

// ------------------------------------------------------------ CSR building
struct EdgeJobs {
  const int* src[5]; const int* dst[5];
};

// ---- MEGA1: grid-fused {fold_ae (MFMA) | hist_rank} -------------------
// r9 analysis: hist_rank (600K device-scope atomic-with-return) is pure
// latency at 6% BW / 0.6% VALU; fold_ae is BW+MFMA with zero atomics; they
// share no data. Fused 4:1 into one launch they co-schedule on every CU,
// collapsing sum(~73us) toward max(~45us). No streams needed — capture-safe.
struct Mega1Args {
  const float* ea[5];
  const int* dst[5];
};

__global__ __launch_bounds__(256) void fold_hist(
    Mega1Args A,
    const unsigned short* __restrict__ Wfh, const unsigned short* __restrict__ Wfl,
    const float* __restrict__ ccv,
    float* __restrict__ aet0, float* __restrict__ aet1, float* __restrict__ aet2,
    int* __restrict__ cnt, int* __restrict__ rank) {
  int b = blockIdx.x;
  int r5 = b % 5;
  if (r5 == 4) {
    // ---- hist_rank role: 2344 blocks, one edge per thread
    int e = (b / 5) * 256 + (int)threadIdx.x;
    if (e >= kETot) return;
    int t = 0;
    while (t < 4 && e >= kEoff[t + 1]) t++;
    int d = A.dst[t][e - kEoff[t]];
    rank[e] = atomicAdd(&cnt[seg_of(t, d)], 1);
    return;
  }
  // ---- fold_ae role: 9375 logical blocks, 16 edges per wave
  int fb = (b / 5) * 4 + r5;
  int w = fb * 4 + ((int)threadIdx.x >> 6);
  int eg0 = w * 16;
  if (eg0 >= kETot) return;
  int t = 0;
  while (t < 4 && eg0 >= kEoff[t + 1]) t++;      // all relation sizes % 16 == 0
  int lane = threadIdx.x & 63;
  int l16 = lane & 15, quad = lane >> 4;
  int el = eg0 - kEoff[t] + l16;                 // this lane's edge row
  const float4* p4 = (const float4*)(A.ea[t] + (size_t)el * 32 + quad * 8);
  float4 a = p4[0], bb = p4[1];
  float xv[8] = {a.x, a.y, a.z, a.w, bb.x, bb.y, bb.z, bb.w};
  unsigned hi[8], lo[8];
#pragma unroll
  for (int i = 0; i < 8; i++) {
    unsigned short h = f2b(xv[i]);
    hi[i] = h;
    lo[i] = f2b(xv[i] - b2f(h));
  }
  int4 hraw = make_int4((int)(hi[0] | (hi[1] << 16)), (int)(hi[2] | (hi[3] << 16)),
                        (int)(hi[4] | (hi[5] << 16)), (int)(hi[6] | (hi[7] << 16)));
  int4 lraw = make_int4((int)(lo[0] | (lo[1] << 16)), (int)(lo[2] | (lo[3] << 16)),
                        (int)(lo[4] | (lo[5] << 16)), (int)(lo[6] | (lo[7] << 16)));
  bf16x8 Ah = __builtin_bit_cast(bf16x8, hraw);
  bf16x8 Al = __builtin_bit_cast(bf16x8, lraw);
  size_t wb = (size_t)t * 1024 + (size_t)l16 * 32 + quad * 8;
  bf16x8 B0h = __builtin_bit_cast(bf16x8, *(const int4*)(Wfh + wb));
  bf16x8 B0l = __builtin_bit_cast(bf16x8, *(const int4*)(Wfl + wb));
  bf16x8 B1h = __builtin_bit_cast(bf16x8, *(const int4*)(Wfh + wb + 512));
  bf16x8 B1l = __builtin_bit_cast(bf16x8, *(const int4*)(Wfl + wb + 512));
  float4 c0 = *(const float4*)(ccv + t * 32 + quad * 4);
  float4 c1 = *(const float4*)(ccv + t * 32 + 16 + quad * 4);
  f32x4 acc0 = {c0.x, c0.y, c0.z, c0.w};
  f32x4 acc1 = {c1.x, c1.y, c1.z, c1.w};
  acc0 = __builtin_amdgcn_mfma_f32_16x16x32_bf16(B0h, Ah, acc0, 0, 0, 0);
  acc0 = __builtin_amdgcn_mfma_f32_16x16x32_bf16(B0l, Ah, acc0, 0, 0, 0);
  acc0 = __builtin_amdgcn_mfma_f32_16x16x32_bf16(B0h, Al, acc0, 0, 0, 0);
  acc1 = __builtin_amdgcn_mfma_f32_16x16x32_bf16(B1h, Ah, acc1, 0, 0, 0);
  acc1 = __builtin_amdgcn_mfma_f32_16x16x32_bf16(B1l, Ah, acc1, 0, 0, 0);
  acc1 = __builtin_amdgcn_mfma_f32_16x16x32_bf16(B1h, Al, acc1, 0, 0, 0);
  int eg = eg0 + l16;
  float4 o = make_float4(acc0[0], acc0[1], acc0[2], acc0[3]);
  if (quad == 0)      *(float4*)(aet0 + (size_t)eg * 8)     = o;
  else if (quad == 1) *(float4*)(aet0 + (size_t)eg * 8 + 4) = o;
  else if (quad == 2) *(float4*)(aet1 + (size_t)eg * 8)     = o;
  else                *(float4*)(aet1 + (size_t)eg * 8 + 4) = o;
  if (quad == 0) aet2[eg] = acc1[0];
}

// scatter: atomic-free. p = rs[seg] + rank[e]; one packed 16B store per edge.
__global__ void scatter_b(EdgeJobs J, const int* __restrict__ rs,
                          const int* __restrict__ rank, int4* __restrict__ edat) {
  int e = blockIdx.x * 256 + threadIdx.x;
  if (e >= kETot) return;
  int t = 0;
  while (t < 4 && e >= kEoff[t + 1]) t++;
  int el = e - kEoff[t];
  int s = J.src[t][el];
  int d = J.dst[t][el];
  int p = rs[seg_of(t, d)] + rank[e];
  edat[p] = make_int4(e, ((s + kSoff[t]) << 3) | t, ((d + kDoff[t]) << 3) | t,
                      s + kRoff[t]);
}

__global__ void scan_blocks(const int* __restrict__ in, int* __restrict__ out,
                            int* __restrict__ bsums, int n) {
  __shared__ int sh[256];
  int t = threadIdx.x;
  int base = blockIdx.x * 1024 + t * 4;
  int v[4]; int s = 0;
#pragma unroll
  for (int j = 0; j < 4; j++) { v[j] = (base + j < n) ? in[base + j] : 0; s += v[j]; }
  sh[t] = s;
  __syncthreads();
  for (int off = 1; off < 256; off <<= 1) {
    int x = (t >= off) ? sh[t - off] : 0;
    __syncthreads();
    sh[t] += x;
    __syncthreads();
  }
  int run = sh[t] - s;
#pragma unroll
  for (int j = 0; j < 4; j++) { if (base + j < n) out[base + j] = run; run += v[j]; }
  if (t == 255) bsums[blockIdx.x] = sh[255];
}

__global__ void scan_carry(int* bsums, int nb, int* sentinel) {
  if (threadIdx.x == 0 && blockIdx.x == 0) {
    int run = 0;
    for (int b = 0; b < nb; b++) { int x = bsums[b]; bsums[b] = run; run += x; }
    *sentinel = run;
  }
}

__global__ void scan_add(int* __restrict__ out, const int* __restrict__ bsums, int n) {
  int base = blockIdx.x * 1024 + threadIdx.x * 4;
  int c = bsums[blockIdx.x];
#pragma unroll
  for (int j = 0; j < 4; j++) if (base + j < n) out[base + j] += c;
}

// ------------- per-layer logit pass, streaming in CSR order.
__global__ __launch_bounds__(256) void pass_a8(const int4* __restrict__ edat,
                                               const float* __restrict__ aet,
                                               const float* __restrict__ AS,
                                               float* __restrict__ logits) {
  int p = blockIdx.x * 256 + threadIdx.x;
  if (p >= kETot) return;
  int4 ed = edat[p];
  int e = ed.x, sv = ed.y, dv = ed.z;
  int t = sv & 7;
  const float4* asp = (const float4*)(AS + (size_t)(sv >> 3) * 80 + t * 8);
  const float4* adp = (const float4*)(AS + (size_t)(dv >> 3) * 80 + (5 + t) * 8);
  const float4* aep = (const float4*)(aet + (size_t)e * 8);
  float4 s0 = asp[0], s1 = asp[1];
  float4 d0 = adp[0], d1 = adp[1];
  float4 e0 = aep[0], e1 = aep[1];
  float v[8] = {s0.x + d0.x + e0.x, s0.y + d0.y + e0.y, s0.z + d0.z + e0.z, s0.w + d0.w + e0.w,
                s1.x + d1.x + e1.x, s1.y + d1.y + e1.y, s1.z + d1.z + e1.z, s1.w + d1.w + e1.w};
#pragma unroll
  for (int j = 0; j < 8; j++) v[j] = v[j] > 0.f ? v[j] : 0.2f * v[j];
  float4* L = (float4*)(logits + (size_t)p * 8);
  L[0] = make_float4(v[0], v[1], v[2], v[3]);
  L[1] = make_float4(v[4], v[5], v[6], v[7]);
}

__global__ __launch_bounds__(256) void pass_a1(const int4* __restrict__ edat,
                                               const float* __restrict__ aet2,
                                               const float* __restrict__ AS,
                                               float* __restrict__ logits) {
  int p = blockIdx.x * 256 + threadIdx.x;
  if (p >= kETot) return;
  int4 ed = edat[p];
  int e = ed.x, sv = ed.y, dv = ed.z;
  int t = sv & 7;
  float v = aet2[e] + AS[(size_t)(sv >> 3) * 16 + t] + AS[(size_t)(dv >> 3) * 16 + 5 + t];
  v = v > 0.f ? v : 0.2f * v;
  logits[p] = v;
}

// ------- segment softmax per (dst,relation) sub-segment, in place -> alpha
// Register-resident fast path (n<=256, >99% of segments): ONE read pass into
// registers + ONE write pass, vs 3 dependent global round-trips.
template <int H>
__global__ void softmax_k(const int* __restrict__ rs, float* __restrict__ lg) {
  int g = (int)((blockIdx.x * (size_t)blockDim.x + threadIdx.x) >> 6);
  int lane = threadIdx.x & 63;
  if (g >= kSeg) return;
  int start = rs[g], end = rs[g + 1];
  int n = (end - start) * H;
  if (n == 0) return;
  float* L = lg + (size_t)start * H;
  if (n <= 256) {
    float v[4];
#pragma unroll
    for (int j = 0; j < 4; j++) {
      int idx = lane + 64 * j;
      v[j] = (idx < n) ? L[idx] : -3.0e38f;
    }
    float m = fmaxf(fmaxf(v[0], v[1]), fmaxf(v[2], v[3]));
    if (H == 8) {
      m = fmaxf(m, __shfl_xor(m, 8));
      m = fmaxf(m, __shfl_xor(m, 16));
      m = fmaxf(m, __shfl_xor(m, 32));
    } else {
#pragma unroll
      for (int off = 1; off < 64; off <<= 1) m = fmaxf(m, __shfl_xor(m, off));
    }
    float s = 0.f;
#pragma unroll
    for (int j = 0; j < 4; j++) {
      v[j] = __expf(v[j] - m);   // masked lanes: exp(-huge) = 0
      s += v[j];
    }
    if (H == 8) {
      s += __shfl_xor(s, 8);
      s += __shfl_xor(s, 16);
      s += __shfl_xor(s, 32);
    } else {
#pragma unroll
      for (int off = 1; off < 64; off <<= 1) s += __shfl_xor(s, off);
    }
    float inv = 1.f / (s + 1e-16f);
#pragma unroll
    for (int j = 0; j < 4; j++) {
      int idx = lane + 64 * j;
      if (idx < n) L[idx] = v[j] * inv;
    }
    return;
  }
  // fallback (large machine segments at H=8): original 3-pass loop
  float m = -3.0e38f;
  for (int idx = lane; idx < n; idx += 64) m = fmaxf(m, L[idx]);
  if (H == 8) {
    m = fmaxf(m, __shfl_xor(m, 8));
    m = fmaxf(m, __shfl_xor(m, 16));
    m = fmaxf(m, __shfl_xor(m, 32));
  } else {
#pragma unroll
    for (int off = 1; off < 64; off <<= 1) m = fmaxf(m, __shfl_xor(m, off));
  }
  float s = 0.f;
  for (int idx = lane; idx < n; idx += 64) {
    float ex = __expf(L[idx] - m);
    L[idx] = ex;
    s += ex;
  }
  if (H == 8) {
    s += __shfl_xor(s, 8);
    s += __shfl_xor(s, 16);
    s += __shfl_xor(s, 32);
  } else {
#pragma unroll
    for (int off = 1; off < 64; off <<= 1) s += __shfl_xor(s, off);
  }
  float inv = 1.f / (s + 1e-16f);
  for (int idx = lane; idx < n; idx += 64) L[idx] *= inv;
}

// --------------- unified gather: agg[g] = sum over node's sub-segments of alpha*xs
template <int H>
__global__ void gat_gather_u(const int* __restrict__ rs, const int4* __restrict__ edat,
                             const float* __restrict__ alpha,
                             const unsigned short* __restrict__ xs,
                             float* __restrict__ agg) {
  int g = (int)((blockIdx.x * (size_t)blockDim.x + threadIdx.x) >> 6);
  int lane = threadIdx.x & 63;
  if (g >= kNTot) return;
  int start, end;
  if (g < 50000)      { start = rs[3 * g];              end = rs[3 * g + 3]; }
  else if (g < 51000) { int m = g - 50000; start = rs[150000 + m]; end = rs[150001 + m]; }
  else                { int j = g - 51000; start = rs[151000 + j]; end = rs[151001 + j]; }
  int deg = end - start;
  int l16 = lane & 15, quad = lane >> 4;
  int h = (H == 8) ? (l16 >> 1) : 0;
  float acc[8] = {0.f, 0.f, 0.f, 0.f, 0.f, 0.f, 0.f, 0.f};
  for (int base = 0; base < deg; base += 64) {
    int nchunk = deg - base; if (nchunk > 64) nchunk = 64;
    int sv = (lane < nchunk) ? edat[start + base + lane].w : 0;
    for (int i = 0; i < nchunk; i += 4) {
      int e = i + quad;
      bool act = e < nchunk;
      int s = __shfl(sv, act ? e : 0);
      float w = act ? alpha[(size_t)(start + base + e) * H + h] : 0.f;
      int4 raw = *(const int4*)(xs + (size_t)s * HID + l16 * 8);
      unsigned ua[4] = {(unsigned)raw.x, (unsigned)raw.y, (unsigned)raw.z, (unsigned)raw.w};
#pragma unroll
      for (int j = 0; j < 4; j++) {
        acc[2 * j]     += w * __uint_as_float(ua[j] << 16);
        acc[2 * j + 1] += w * __uint_as_float(ua[j] & 0xFFFF0000u);
      }
    }
  }
#pragma unroll
  for (int j = 0; j < 8; j++) {
    acc[j] += __shfl_xor(acc[j], 16);
    acc[j] += __shfl_xor(acc[j], 32);
  }
  if (quad == 0) {
    float* p = agg + (size_t)g * HID + l16 * 8;
    *(float4*)p = make_float4(acc[0], acc[1], acc[2], acc[3]);
    *(float4*)(p + 4) = make_float4(acc[4], acc[5], acc[6], acc[7]);
  }
}

// ------------------------------------------------- BatchNorm column stats
__global__ void colstats_b(const float* __restrict__ x, float* __restrict__ stats) {
  static constexpr int bpref[4] = {0, 384, 400, 448};
  static constexpr int rowoff[4] = {0, 50000, 51000, 56000};
  int b = blockIdx.x;
  int t = 0;
  while (t < 2 && b >= bpref[t + 1]) t++;
  int bl = b - bpref[t], nb = bpref[t + 1] - bpref[t];
  int tid = threadIdx.x;
  int col = tid & 127, half = tid >> 7;
  float s = 0.f, q = 0.f;
  for (int r = rowoff[t] + bl * 2 + half; r < rowoff[t + 1]; r += nb * 2) {
    float v = x[(size_t)r * HID + col];
    s += v; q += v * v;
  }
  __shared__ float ls[256], lq[256];
  ls[tid] = s; lq[tid] = q;
  __syncthreads();
  if (tid < 128) {
    s = ls[tid] + ls[tid + 128];
    q = lq[tid] + lq[tid + 128];
    unsafeAtomicAdd(&stats[t * 256 + col], s);
    unsafeAtomicAdd(&stats[t * 256 + 128 + col], q);
  }
}

// --- BN apply + ReLU + residual: fp32 agg (in-place -> new x) + bf16 shadow
__global__ void bn_apply_b(float* __restrict__ agg, const float* __restrict__ xold,
                           unsigned short* __restrict__ xnb, const float* __restrict__ stats,
                           const float* __restrict__ gammaL, const float* __restrict__ betaL,
                           int relu) {
  size_t i = blockIdx.x * (size_t)blockDim.x + threadIdx.x;
  if (i >= (size_t)kNTot * 32) return;
  int row = (int)(i >> 5);
  int t = (row < 50000) ? 0 : (row < 51000 ? 1 : 2);
  float invN = (t == 0) ? (1.f / 50000.f) : (t == 1 ? (1.f / 1000.f) : (1.f / 5000.f));
  const float* st = stats + t * 256;
  const float* gm = gammaL + t * HID;
  const float* bt = betaL + t * HID;
  int c4 = ((int)(i & 31)) * 4;
  float4 av = ((const float4*)agg)[i];
  float4 xv = ((const float4*)xold)[i];
  float a[4] = {av.x, av.y, av.z, av.w};
  float xo[4] = {xv.x, xv.y, xv.z, xv.w};
  float o[4];
#pragma unroll
  for (int j = 0; j < 4; j++) {
    int c = c4 + j;
    float mu = st[c] * invN;
    float var = st[128 + c] * invN - mu * mu;
    float g = gm[c] * rsqrtf(var + 1e-5f);
    float v = (a[j] - mu) * g + bt[c];
    if (relu) v = fmaxf(v, 0.f);
    o[j] = v + xo[j];
  }
  ((float4*)agg)[i] = make_float4(o[0], o[1], o[2], o[3]);
  ((ushort4*)xnb)[i] = make_ushort4(f2b(o[0]), f2b(o[1]), f2b(o[2]), f2b(o[3]));
}

// ============================================================== host driver
extern "C" void kernel_launch(void* const* d_in, const int* in_sizes, int n_in,
                              void* d_out, int out_size, void* d_ws, size_t ws_size,
                              hipStream_t stream) {
  const float* x_in[3] = {(const float*)d_in[0], (const float*)d_in[1], (const float*)d_in[2]};
  const int* ei[5];
  const float* ea[5];
  for (int t = 0; t < 5; t++) {
    ei[t] = (const int*)d_in[3 + 2 * t];
    ea[t] = (const float*)d_in[4 + 2 * t];
  }
  const float* Wn[3]  = {(const float*)d_in[13], (const float*)d_in[15], (const float*)d_in[17]};
  const float* bnb[3] = {(const float*)d_in[14], (const float*)d_in[16], (const float*)d_in[18]};
  const float* Wep   = (const float*)d_in[19];
  const float* bep   = (const float*)d_in[20];
  const float* Wg    = (const float*)d_in[21];
  const float* att_s = (const float*)d_in[22];
  const float* att_d = (const float*)d_in[23];
  const float* Wge   = (const float*)d_in[24];
  const float* att_e = (const float*)d_in[25];
  // d_in[26] = bg: cancelled exactly by BatchNorm mean-subtraction; unused.
  const float* gamma = (const float*)d_in[27];
  const float* beta  = (const float*)d_in[28];
  const float* Wo    = (const float*)d_in[29];
  const float* bo    = (const float*)d_in[30];

  float* ws = (float*)d_ws;
  size_t off = 0;
  auto alloc = [&](size_t n) { size_t o = off; off += (n + 255) & ~(size_t)255; return o; };
  auto allocb = [&](size_t n) { return alloc((n + 1) / 2); };

  float* bufA = ws + alloc((size_t)kNTot * HID);   // fp32 x (residual chain)
  float* bufB = ws + alloc((size_t)kNTot * HID);   // fp32 agg / next x
  unsigned short* xcurb = (unsigned short*)(ws + allocb((size_t)kNTot * HID));
  unsigned short* xs_all = (unsigned short*)(ws + allocb((size_t)kRTot * HID));
  unsigned short* WgT  = (unsigned short*)(ws + allocb((size_t)15 * HID * HID));
  unsigned short* WoT  = (unsigned short*)(ws + allocb((size_t)HID * HID));
  unsigned short* WnT_op  = (unsigned short*)(ws + allocb((size_t)HID * 64));
  unsigned short* WnT_ma  = (unsigned short*)(ws + allocb((size_t)HID * 32));
  unsigned short* WnT_job = (unsigned short*)(ws + allocb((size_t)HID * 32));
  unsigned short* VbT  = (unsigned short*)(ws + allocb((size_t)3 * 80 * HID));
  unsigned short* Wfh  = (unsigned short*)(ws + allocb((size_t)5 * 32 * 32));
  unsigned short* Wfl  = (unsigned short*)(ws + allocb((size_t)5 * 32 * 32));
  float* ccv    = ws + alloc((size_t)5 * 32);
  float* Sv     = ws + alloc((size_t)15 * 8 * HID);
  float* Dv     = ws + alloc((size_t)15 * 8 * HID);
  float* w32    = ws + alloc((size_t)15 * 8 * 32);
  float* cv     = ws + alloc((size_t)15 * 8);
  float* stats  = ws + alloc((size_t)3 * 256);
  float* ASbuf  = ws + alloc((size_t)kNTot * 80);
  float* logits = ws + alloc((size_t)kETot * 8 + 64);
  int* rs_all   = (int*)(ws + alloc((size_t)kSeg + 8));
  int4* edat    = (int4*)(ws + alloc((size_t)kETot * 4));  // {e, spack, dpack, ssrc}
  float* aet0   = ws + alloc((size_t)kETot * 8);   // edge-order a_e, layer 0 (H=8)
  float* aet1   = ws + alloc((size_t)kETot * 8);   // layer 1 (H=8)
  float* aet2   = ws + alloc((size_t)kETot);       // layer 2 (H=1)
  // aliases: xinb_* live inside xs_all (consumed before xs_all is written);
  // cnt/rank/bsums live inside logits (CSR build precedes first logit write)
  unsigned short* xinb_op  = xs_all;                          // 3.2M ushorts
  unsigned short* xinb_ma  = xs_all + 3200000;                // 32k ushorts
  unsigned short* xinb_job = xs_all + 3232000;                // 160k ushorts
  int* cnt    = (int*)logits;                       // 156,032 ints
  int* rank   = (int*)(logits + 156032);            // 600,000 ints
  int* bsums  = (int*)(logits + 756288);            // 160 ints
  (void)ws_size; (void)in_sizes; (void)n_in; (void)out_size;

  float* xcur = bufA;
  float* agg  = bufB;

  EdgeJobs EJ;
  for (int t = 0; t < 5; t++) { EJ.src[t] = ei[t]; EJ.dst[t] = ei[t] + kEsz[t]; }

  // -------- prologue: fold tables (needed by mega1) + cnt zero
  hipMemsetAsync(cnt, 0, (size_t)kSeg * 4, stream);
  fold_kernel<<<120, 128, 0, stream>>>(Wg, att_s, att_d, Wge, att_e, Wep, bep,
                                       Sv, Dv, w32, cv);
  build_vb<<<(3 * 80 * HID + 255) / 256, 256, 0, stream>>>(Sv, Dv, VbT);
  build_wf<<<(5 * 32 * 32 + 255) / 256, 256, 0, stream>>>(w32, cv, Wfh, Wfl, ccv);

  // -------- MEGA1: fold_ae ∪ hist_rank, 4:1 interleaved (latency hides under BW)
  Mega1Args MA;
  for (int t = 0; t < 5; t++) { MA.ea[t] = ea[t]; MA.dst[t] = ei[t] + kEsz[t]; }
  fold_hist<<<11720, 256, 0, stream>>>(MA, Wfh, Wfl, ccv, aet0, aet1, aet2, cnt, rank);

  // -------- CSR scan + scatter
  int nb = (kSeg + 1023) / 1024;
  scan_blocks<<<nb, 256, 0, stream>>>(cnt, rs_all, bsums, kSeg);
  scan_carry<<<1, 64, 0, stream>>>(bsums, nb, rs_all + kSeg);
  scan_add<<<nb, 256, 0, stream>>>(rs_all, bsums, kSeg);
  scatter_b<<<(kETot + 255) / 256, 256, 0, stream>>>(EJ, rs_all, rank, edat);

  // -------- bf16 conversions
  conv_pad<<<(kNOp * 64 + 255) / 256, 256, 0, stream>>>(x_in[0], xinb_op, kNOp, 64, 64);
  conv_pad<<<(kNMa * 32 + 255) / 256, 256, 0, stream>>>(x_in[1], xinb_ma, kNMa, 32, 32);
  conv_pad<<<(kNJob * 32 + 255) / 256, 256, 0, stream>>>(x_in[2], xinb_job, kNJob, 16, 32);
  transpose_w<<<(HID * 64 + 255) / 256, 256, 0, stream>>>(Wn[0], WnT_op, 64, HID, 64, 1);
  transpose_w<<<(HID * 32 + 255) / 256, 256, 0, stream>>>(Wn[1], WnT_ma, 32, HID, 32, 1);
  transpose_w<<<(HID * 32 + 255) / 256, 256, 0, stream>>>(Wn[2], WnT_job, 16, HID, 32, 1);
  transpose_w<<<(15 * HID * HID + 255) / 256, 256, 0, stream>>>(Wg, WgT, HID, HID, HID, 15);
  transpose_w<<<(HID * HID + 255) / 256, 256, 0, stream>>>(Wo, WoT, HID, HID, HID, 1);

  // -------- node input projections (fp32 x + bf16 shadow)
  gemm_mfma<2><<<((kNOp + 15) / 16 + 3) / 4, 256, 0, stream>>>(
      xinb_op, WnT_op, bnb[0], xcur, xcurb, kNOp);
  gemm_mfma<1><<<((kNMa + 15) / 16 + 3) / 4, 256, 0, stream>>>(
      xinb_ma, WnT_ma, bnb[1], xcur + (size_t)50000 * HID, xcurb + (size_t)50000 * HID, kNMa);
  gemm_mfma<1><<<((kNJob + 15) / 16 + 3) / 4, 256, 0, stream>>>(
      xinb_job, WnT_job, bnb[2], xcur + (size_t)51000 * HID, xcurb + (size_t)51000 * HID, kNJob);

  for (int l = 0; l < 3; l++) {
    int H = (l < 2) ? 8 : 1;

    // xs for all 5 relations; LDS-staged weights, LDS-bounced coalesced stores
    gemm_xs<<<877, 256, 0, stream>>>(xcurb, WgT + (size_t)l * 5 * HID * HID, xs_all);

    // a_s/a_d for all (relation, head) via one MFMA GEMM
    int asBlocks = ((kNTot + 15) / 16 + 3) / 4;
    if (H == 8)
      gemm_as<80><<<asBlocks, 256, 0, stream>>>(xcurb, VbT + (size_t)l * 80 * HID, ASbuf, kNTot);
    else
      gemm_as<16><<<asBlocks, 256, 0, stream>>>(xcurb, VbT + (size_t)l * 80 * HID, ASbuf, kNTot);

    // logits: streaming pass over CSR-ordered edges (aet gathered via edat.x)
    int pblocks = (kETot + 255) / 256;
    if (H == 8) {
      const float* aeL = (l == 0) ? aet0 : aet1;
      pass_a8<<<pblocks, 256, 0, stream>>>(edat, aeL, ASbuf, logits);
    } else {
      pass_a1<<<pblocks, 256, 0, stream>>>(edat, aet2, ASbuf, logits);
    }

    if (H == 8) {
      softmax_k<8><<<((size_t)kSeg * 64 + 255) / 256, 256, 0, stream>>>(rs_all, logits);
      gat_gather_u<8><<<((size_t)kNTot * 64 + 255) / 256, 256, 0, stream>>>(
          rs_all, edat, logits, xs_all, agg);
    } else {
      softmax_k<1><<<((size_t)kSeg * 64 + 255) / 256, 256, 0, stream>>>(rs_all, logits);
      gat_gather_u<1><<<((size_t)kNTot * 64 + 255) / 256, 256, 0, stream>>>(
          rs_all, edat, logits, xs_all, agg);
    }

    hipMemsetAsync(stats, 0, 3 * 256 * 4, stream);
    colstats_b<<<448, 256, 0, stream>>>(agg, stats);
    bn_apply_b<<<(unsigned)(((size_t)kNTot * 32 + 255) / 256), 256, 0, stream>>>(
        agg, xcur, xcurb, stats, gamma + (size_t)l * 3 * HID, beta + (size_t)l * 3 * HID,
        (l < 2) ? 1 : 0);
    float* tmp = xcur; xcur = agg; agg = tmp;   // agg now holds new fp32 x
  }

  gemm_mfma<4><<<((kNOp + 15) / 16 + 3) / 4, 256, 0, stream>>>(
      xcurb, WoT, bo, (float*)d_out, nullptr, kNOp);
}

// Round 11
// 833.841 us; speedup vs baseline: 1.0274x; 1.0104x over previous
//
#include <hip/hip_runtime.h>
#include <cstdint>

#define HID 128

static constexpr int kNOp = 50000, kNMa = 1000, kNJob = 5000;
static constexpr int kNTot = 56000;                 // op | ma | job global node space
static constexpr int kETot = 600000;
static constexpr int kSeg = 156000;                 // (dst,relation) sub-segments
static constexpr int kEsz[5]   = {150000, 100000, 150000, 100000, 100000};
static constexpr int kSrcT[5]  = {0, 0, 1, 2, 0};
static constexpr int kDstT[5]  = {0, 1, 0, 0, 2};
static constexpr int kNodeOff[3] = {0, 50000, 51000};
static constexpr int kSoff[5]  = {0, 0, 50000, 51000, 0};
static constexpr int kDoff[5]  = {0, 50000, 0, 0, 51000};
static constexpr int kEoff[6]  = {0, 150000, 250000, 400000, 500000, 600000};
static constexpr int kRoff[5]  = {0, 50000, 100000, 101000, 106000};  // xs_all row offset (src counts)
static constexpr int kRTot = 156000;

typedef __attribute__((ext_vector_type(8))) __bf16 bf16x8;
typedef __attribute__((ext_vector_type(4))) float f32x4;

__device__ inline unsigned short f2b(float f) {
  unsigned u = __float_as_uint(f);
  unsigned r = (u + 0x7FFFu + ((u >> 16) & 1u)) >> 16;
  return (unsigned short)r;
}
__device__ inline float b2f(unsigned short u) {
  return __uint_as_float(((unsigned)u) << 16);
}

// (dst,relation) -> softmax sub-segment id; op sub-segments contiguous per node
__device__ inline int seg_of(int t, int d) {
  if (t == 0) return 3 * d;
  if (t == 2) return 3 * d + 1;
  if (t == 3) return 3 * d + 2;
  if (t == 1) return 150000 + d;
  return 151000 + d;  // t4
}

// ------------------------------------------------ fp32 -> bf16 (pad K to Kp)
__global__ void conv_pad(const float* __restrict__ in, unsigned short* __restrict__ out,
                         int M, int K, int Kp) {
  int i = blockIdx.x * blockDim.x + threadIdx.x;
  if (i >= M * Kp) return;
  int r = i / Kp, c = i - r * Kp;
  out[i] = (c < K) ? f2b(in[(size_t)r * K + c]) : (unsigned short)0;
}

// ---------------------- W[K x N] fp32 -> Wt[N x Kp] bf16 (batched, zero-pad K)
__global__ void transpose_w(const float* __restrict__ W, unsigned short* __restrict__ Wt,
                            int K, int N, int Kp, int nmat) {
  int i = blockIdx.x * blockDim.x + threadIdx.x;
  int per = N * Kp;
  if (i >= nmat * per) return;
  int b = i / per, rem = i - b * per;
  int n = rem / Kp, k = rem - n * Kp;
  Wt[i] = (k < K) ? f2b(W[(size_t)b * K * N + (size_t)k * N + n]) : (unsigned short)0;
}

// --------------------------------------------- plain bf16 MFMA GEMM (N=128)
// OPERAND-SWAPPED: acc = mfma(W_frag, x_frag) -> D[wcol][xrow]; each thread
// holds 4 CONSECUTIVE output cols of one x-row -> float4/ushort4 stores.
template <int KC>   // K = KC*32
__global__ __launch_bounds__(256) void gemm_mfma(
    const unsigned short* __restrict__ A, const unsigned short* __restrict__ Bt,
    const float* __restrict__ bias, float* __restrict__ Cf,
    unsigned short* __restrict__ Cb, int M) {
  const int K = KC * 32;
  int w = blockIdx.x * 4 + (threadIdx.x >> 6);
  int m0 = w * 16;
  if (m0 >= M) return;
  int lane = threadIdx.x & 63;
  int l16 = lane & 15, quad = lane >> 4;
  int xrow = m0 + l16; if (xrow >= M) xrow = M - 1;
  bf16x8 xf[KC];
#pragma unroll
  for (int kc = 0; kc < KC; kc++) {
    int4 raw = *(const int4*)(A + (size_t)xrow * K + kc * 32 + quad * 8);
    xf[kc] = __builtin_bit_cast(bf16x8, raw);
  }
  bool wr = (m0 + l16 < M);
  int row = m0 + l16;
#pragma unroll
  for (int nt = 0; nt < 8; nt++) {
    f32x4 acc = {0.f, 0.f, 0.f, 0.f};
#pragma unroll
    for (int kc = 0; kc < KC; kc++) {
      int4 braw = *(const int4*)(Bt + (size_t)(nt * 16 + l16) * K + kc * 32 + quad * 8);
      acc = __builtin_amdgcn_mfma_f32_16x16x32_bf16(
          __builtin_bit_cast(bf16x8, braw), xf[kc], acc, 0, 0, 0);
    }
    int col0 = nt * 16 + quad * 4;
    float o[4];
#pragma unroll
    for (int r = 0; r < 4; r++) o[r] = acc[r] + (bias ? bias[col0 + r] : 0.f);
    if (wr) {
      if (Cf) *(float4*)(Cf + (size_t)row * HID + col0) = make_float4(o[0], o[1], o[2], o[3]);
      if (Cb) *(ushort4*)(Cb + (size_t)row * HID + col0) =
                  make_ushort4(f2b(o[0]), f2b(o[1]), f2b(o[2]), f2b(o[3]));
    }
  }
}

// ------------- fused xs GEMM with LDS-staged weights + LDS-bounced stores.
// Block = 64 rows (4 waves x 16). Per relation: Wg[t] (32KB) staged ONCE per
// block into LDS; out tiles bounced through LDS -> 4 x 1KB coalesced stores.
__global__ __launch_bounds__(256) void gemm_xs(const unsigned short* __restrict__ x,
                                               const unsigned short* __restrict__ WgTl,
                                               unsigned short* __restrict__ xs) {
  __shared__ __align__(16) unsigned short Bs[128 * 136];    // +16B row pad (bank)
  __shared__ __align__(16) unsigned short Os[4][16 * 136];
  // blocks [0,782): op; [782,798): ma; [798,877): job  (64 rows per block)
  int b = blockIdx.x;
  int grp = (b < 782) ? 0 : (b < 798 ? 1 : 2);
  int sb   = (grp == 0) ? 0     : (grp == 1 ? 782   : 798);
  int M    = (grp == 0) ? 50000 : (grp == 1 ? 1000  : 5000);
  int xoff = (grp == 0) ? 0     : (grp == 1 ? 50000 : 51000);
  int tid = threadIdx.x;
  int wid = tid >> 6, lane = tid & 63;
  int l16 = lane & 15, quad = lane >> 4;
  int m0 = (b - sb) * 64 + wid * 16;
  int xrow = m0 + l16; if (xrow >= M) xrow = M - 1;
  bf16x8 xf[4];
#pragma unroll
  for (int kc = 0; kc < 4; kc++) {
    int4 raw = *(const int4*)(x + (size_t)(xoff + xrow) * HID + kc * 32 + quad * 8);
    xf[kc] = __builtin_bit_cast(bf16x8, raw);
  }
  int nrel = (grp == 0) ? 3 : 1;
  int rel0  = (grp == 0) ? 0 : (grp == 1 ? 2 : 3);
  int roff0 = (grp == 0) ? 0 : (grp == 1 ? 100000 : 101000);
  int rels[3]  = {rel0, 1, 4};
  int roffs[3] = {roff0, 50000, 106000};
  for (int rr = 0; rr < nrel; rr++) {
    int t = rels[rr];
    unsigned short* Cb = xs + (size_t)roffs[rr] * HID;
    __syncthreads();   // all waves done reading previous Bs
    const unsigned short* Wsrc = WgTl + (size_t)t * HID * HID;
    for (int c = tid; c < 2048; c += 256) {       // 2048 x int4 = 32KB, coalesced
      int row = c >> 4, k8 = c & 15;
      *(int4*)&Bs[row * 136 + k8 * 8] = *(const int4*)(Wsrc + row * 128 + k8 * 8);
    }
    __syncthreads();
#pragma unroll
    for (int nt = 0; nt < 8; nt++) {
      f32x4 acc = {0.f, 0.f, 0.f, 0.f};
#pragma unroll
      for (int kc = 0; kc < 4; kc++) {
        bf16x8 bfr = *(const bf16x8*)&Bs[(nt * 16 + l16) * 136 + kc * 32 + quad * 8];
        acc = __builtin_amdgcn_mfma_f32_16x16x32_bf16(bfr, xf[kc], acc, 0, 0, 0);
      }
      *(ushort4*)&Os[wid][l16 * 136 + nt * 16 + quad * 4] =
          make_ushort4(f2b(acc[0]), f2b(acc[1]), f2b(acc[2]), f2b(acc[3]));
    }
    // wave-private tile -> global, 4 x 1KB contiguous store instructions
#pragma unroll
    for (int i = 0; i < 4; i++) {
      int g = i * 1024 + lane * 16;     // byte offset within the 4KB tile
      int row = g >> 8;
      int colb = g & 255;
      int4 v = *(const int4*)((const char*)&Os[wid][0] + row * 272 + colb);
      if (m0 + row < M)
        *(int4*)((char*)(Cb + (size_t)(m0 + row) * HID) + colb) = v;
    }
  }
}

// ---------------- AS GEMM: AS[M x NCOL] = x[M x 128] @ VbT^T, fp32 out
// (operand-swapped -> float4 coalesced stores)
template <int NCOL>
__global__ __launch_bounds__(256) void gemm_as(
    const unsigned short* __restrict__ A, const unsigned short* __restrict__ Bt,
    float* __restrict__ out, int M) {
  int w = blockIdx.x * 4 + (threadIdx.x >> 6);
  int m0 = w * 16;
  if (m0 >= M) return;
  int lane = threadIdx.x & 63;
  int l16 = lane & 15, quad = lane >> 4;
  int xrow = m0 + l16; if (xrow >= M) xrow = M - 1;
  bf16x8 xf[4];
#pragma unroll
  for (int kc = 0; kc < 4; kc++) {
    int4 raw = *(const int4*)(A + (size_t)xrow * HID + kc * 32 + quad * 8);
    xf[kc] = __builtin_bit_cast(bf16x8, raw);
  }
  bool wr = (m0 + l16 < M);
  int row = m0 + l16;
#pragma unroll
  for (int nt = 0; nt < NCOL / 16; nt++) {
    f32x4 acc = {0.f, 0.f, 0.f, 0.f};
#pragma unroll
    for (int kc = 0; kc < 4; kc++) {
      int4 braw = *(const int4*)(Bt + (size_t)(nt * 16 + l16) * HID + kc * 32 + quad * 8);
      acc = __builtin_amdgcn_mfma_f32_16x16x32_bf16(
          __builtin_bit_cast(bf16x8, braw), xf[kc], acc, 0, 0, 0);
    }
    if (wr) {
      int col0 = nt * 16 + quad * 4;
      *(float4*)(out + (size_t)row * NCOL + col0) = make_float4(acc[0], acc[1], acc[2], acc[3]);
    }
  }
}

// ------------------------------------------------- fold attention vectors
// S[lt,h,k] = sum_c Wg[k][hC+c]*att_s[hC+c]; D likewise; w32/cvec edge fold.
__global__ void fold_kernel(const float* __restrict__ Wg, const float* __restrict__ att_s,
                            const float* __restrict__ att_d, const float* __restrict__ Wge,
                            const float* __restrict__ att_e, const float* __restrict__ Wep,
                            const float* __restrict__ bep,
                            float* __restrict__ S, float* __restrict__ D,
                            float* __restrict__ w32, float* __restrict__ cvec) {
  int idx = blockIdx.x;          // (l*5+t)*8 + h
  int h = idx & 7, lt = idx >> 3;
  int l = lt / 5;
  int H = (l < 2) ? 8 : 1, C = HID / H;
  if (h >= H) return;
  int k = threadIdx.x;           // 0..127
  int t = lt % 5;
  const float* wg  = Wg  + (size_t)lt * HID * HID;
  const float* wge = Wge + (size_t)lt * HID * HID;
  const float* as_ = att_s + (size_t)lt * HID + h * C;
  const float* ad_ = att_d + (size_t)lt * HID + h * C;
  const float* ae_ = att_e + (size_t)lt * HID + h * C;
  float s = 0.f, d = 0.f, v = 0.f;
  for (int c = 0; c < C; c++) {
    float wr = wg[(size_t)k * HID + h * C + c];
    s += wr * as_[c];
    d += wr * ad_[c];
    v += wge[(size_t)k * HID + h * C + c] * ae_[c];
  }
  S[(size_t)idx * HID + k] = s;
  D[(size_t)idx * HID + k] = d;
  __shared__ float vs[HID];
  vs[k] = v;
  __syncthreads();
  if (k < 32) {
    const float* wp = Wep + (size_t)t * 32 * HID + (size_t)k * HID;
    float a = 0.f;
    for (int j = 0; j < HID; j++) a += wp[j] * vs[j];
    w32[(size_t)idx * 32 + k] = a;
  }
  if (k == 32) {
    const float* bp = bep + (size_t)t * HID;
    float a = 0.f;
    for (int j = 0; j < HID; j++) a += bp[j] * vs[j];
    cvec[idx] = a;
  }
}

// ------ pack folded S/D vectors into bf16 Bt layout: VbT[l][col][k], col=(v,h)
// v in 0..9: v<5 -> S of relation v; v>=5 -> D of relation v-5. 80 cols/layer.
__global__ void build_vb(const float* __restrict__ Sv, const float* __restrict__ Dv,
                         unsigned short* __restrict__ VbT) {
  int i = blockIdx.x * 256 + threadIdx.x;
  if (i >= 3 * 80 * HID) return;
  int l = i / (80 * HID), rem = i % (80 * HID);
  int col = rem / HID, k = rem % HID;
  int H = (l < 2) ? 8 : 1;
  float val = 0.f;
  if (col < 10 * H) {
    int v = col / H, h = col % H;
    const float* base = (v < 5) ? Sv : Dv;
    int t = (v < 5) ? v : v - 5;
    val = base[((size_t)(l * 5 + t) * 8 + h) * HID + k];
  }
  VbT[i] = f2b(val);
}

// ---- build the fold-GEMM B matrix: Wf[t][col 0..31][k 0..31] bf16 hi/lo.
// col 0-7 = layer0 heads, 8-15 = layer1 heads, 16 = layer2, 17-31 = zero.
__global__ void build_wf(const float* __restrict__ w32, const float* __restrict__ cv,
                         unsigned short* __restrict__ Wfh, unsigned short* __restrict__ Wfl,
                         float* __restrict__ ccv) {
  int i = blockIdx.x * 256 + threadIdx.x;
  if (i >= 5 * 32 * 32) return;
  int t = i >> 10, rem = i & 1023;
  int col = rem >> 5, k = rem & 31;
  float val = 0.f, c = 0.f;
  if (col < 8)        { val = w32[((size_t)((0 * 5 + t) * 8 + col)) * 32 + k];       c = cv[(0 * 5 + t) * 8 + col]; }
  else if (col < 16)  { val = w32[((size_t)((1 * 5 + t) * 8 + (col - 8))) * 32 + k]; c = cv[(1 * 5 + t) * 8 + col - 8]; }
  else if (col == 16) { val = w32[((size_t)((2 * 5 + t) * 8 + 0)) * 32 + k];         c = cv[(2 * 5 + t) * 8]; }
  unsigned short h = f2b(val);
  Wfh[i] = h;
  Wfl[i] = f2b(val - b2f(h));
  if (k == 0) ccv[t * 32 + col] = c;
}

// ------------------------------------------------------------ CSR building
struct EdgeJobs {
  const int* src[5]; const int* dst[5];
};

// ---- MEGA1: grid-fused {fold_ae (MFMA) | hist_rank} -------------------
struct Mega1Args {
  const float* ea[5];
  const int* dst[5];
};

__global__ __launch_bounds__(256) void fold_hist(
    Mega1Args A,
    const unsigned short* __restrict__ Wfh, const unsigned short* __restrict__ Wfl,
    const float* __restrict__ ccv,
    float* __restrict__ aet0, float* __restrict__ aet1, float* __restrict__ aet2,
    int* __restrict__ cnt, int* __restrict__ rank) {
  int b = blockIdx.x;
  int r5 = b % 5;
  if (r5 == 4) {
    // ---- hist_rank role: 2344 blocks, one edge per thread
    int e = (b / 5) * 256 + (int)threadIdx.x;
    if (e >= kETot) return;
    int t = 0;
    while (t < 4 && e >= kEoff[t + 1]) t++;
    int d = A.dst[t][e - kEoff[t]];
    rank[e] = atomicAdd(&cnt[seg_of(t, d)], 1);
    return;
  }
  // ---- fold_ae role: 9375 logical blocks, 16 edges per wave
  int fb = (b / 5) * 4 + r5;
  int w = fb * 4 + ((int)threadIdx.x >> 6);
  int eg0 = w * 16;
  if (eg0 >= kETot) return;
  int t = 0;
  while (t < 4 && eg0 >= kEoff[t + 1]) t++;      // all relation sizes % 16 == 0
  int lane = threadIdx.x & 63;
  int l16 = lane & 15, quad = lane >> 4;
  int el = eg0 - kEoff[t] + l16;                 // this lane's edge row
  const float4* p4 = (const float4*)(A.ea[t] + (size_t)el * 32 + quad * 8);
  float4 a = p4[0], bb = p4[1];
  float xv[8] = {a.x, a.y, a.z, a.w, bb.x, bb.y, bb.z, bb.w};
  unsigned hi[8], lo[8];
#pragma unroll
  for (int i = 0; i < 8; i++) {
    unsigned short h = f2b(xv[i]);
    hi[i] = h;
    lo[i] = f2b(xv[i] - b2f(h));
  }
  int4 hraw = make_int4((int)(hi[0] | (hi[1] << 16)), (int)(hi[2] | (hi[3] << 16)),
                        (int)(hi[4] | (hi[5] << 16)), (int)(hi[6] | (hi[7] << 16)));
  int4 lraw = make_int4((int)(lo[0] | (lo[1] << 16)), (int)(lo[2] | (lo[3] << 16)),
                        (int)(lo[4] | (lo[5] << 16)), (int)(lo[6] | (lo[7] << 16)));
  bf16x8 Ah = __builtin_bit_cast(bf16x8, hraw);
  bf16x8 Al = __builtin_bit_cast(bf16x8, lraw);
  size_t wb = (size_t)t * 1024 + (size_t)l16 * 32 + quad * 8;
  bf16x8 B0h = __builtin_bit_cast(bf16x8, *(const int4*)(Wfh + wb));
  bf16x8 B0l = __builtin_bit_cast(bf16x8, *(const int4*)(Wfl + wb));
  bf16x8 B1h = __builtin_bit_cast(bf16x8, *(const int4*)(Wfh + wb + 512));
  bf16x8 B1l = __builtin_bit_cast(bf16x8, *(const int4*)(Wfl + wb + 512));
  float4 c0 = *(const float4*)(ccv + t * 32 + quad * 4);
  float4 c1 = *(const float4*)(ccv + t * 32 + 16 + quad * 4);
  f32x4 acc0 = {c0.x, c0.y, c0.z, c0.w};
  f32x4 acc1 = {c1.x, c1.y, c1.z, c1.w};
  acc0 = __builtin_amdgcn_mfma_f32_16x16x32_bf16(B0h, Ah, acc0, 0, 0, 0);
  acc0 = __builtin_amdgcn_mfma_f32_16x16x32_bf16(B0l, Ah, acc0, 0, 0, 0);
  acc0 = __builtin_amdgcn_mfma_f32_16x16x32_bf16(B0h, Al, acc0, 0, 0, 0);
  acc1 = __builtin_amdgcn_mfma_f32_16x16x32_bf16(B1h, Ah, acc1, 0, 0, 0);
  acc1 = __builtin_amdgcn_mfma_f32_16x16x32_bf16(B1l, Ah, acc1, 0, 0, 0);
  acc1 = __builtin_amdgcn_mfma_f32_16x16x32_bf16(B1h, Al, acc1, 0, 0, 0);
  int eg = eg0 + l16;
  float4 o = make_float4(acc0[0], acc0[1], acc0[2], acc0[3]);
  if (quad == 0)      *(float4*)(aet0 + (size_t)eg * 8)     = o;
  else if (quad == 1) *(float4*)(aet0 + (size_t)eg * 8 + 4) = o;
  else if (quad == 2) *(float4*)(aet1 + (size_t)eg * 8)     = o;
  else                *(float4*)(aet1 + (size_t)eg * 8 + 4) = o;
  if (quad == 0) aet2[eg] = acc1[0];
}

// scatter: atomic-free. p = rs[seg] + rank[e]; one packed 16B store per edge.
__global__ void scatter_b(EdgeJobs J, const int* __restrict__ rs,
                          const int* __restrict__ rank, int4* __restrict__ edat) {
  int e = blockIdx.x * 256 + threadIdx.x;
  if (e >= kETot) return;
  int t = 0;
  while (t < 4 && e >= kEoff[t + 1]) t++;
  int el = e - kEoff[t];
  int s = J.src[t][el];
  int d = J.dst[t][el];
  int p = rs[seg_of(t, d)] + rank[e];
  edat[p] = make_int4(e, ((s + kSoff[t]) << 3) | t, ((d + kDoff[t]) << 3) | t,
                      s + kRoff[t]);
}

__global__ void scan_blocks(const int* __restrict__ in, int* __restrict__ out,
                            int* __restrict__ bsums, int n) {
  __shared__ int sh[256];
  int t = threadIdx.x;
  int base = blockIdx.x * 1024 + t * 4;
  int v[4]; int s = 0;
#pragma unroll
  for (int j = 0; j < 4; j++) { v[j] = (base + j < n) ? in[base + j] : 0; s += v[j]; }
  sh[t] = s;
  __syncthreads();
  for (int off = 1; off < 256; off <<= 1) {
    int x = (t >= off) ? sh[t - off] : 0;
    __syncthreads();
    sh[t] += x;
    __syncthreads();
  }
  int run = sh[t] - s;
#pragma unroll
  for (int j = 0; j < 4; j++) { if (base + j < n) out[base + j] = run; run += v[j]; }
  if (t == 255) bsums[blockIdx.x] = sh[255];
}

__global__ void scan_carry(int* bsums, int nb, int* sentinel) {
  if (threadIdx.x == 0 && blockIdx.x == 0) {
    int run = 0;
    for (int b = 0; b < nb; b++) { int x = bsums[b]; bsums[b] = run; run += x; }
    *sentinel = run;
  }
}

__global__ void scan_add(int* __restrict__ out, const int* __restrict__ bsums, int n) {
  int base = blockIdx.x * 1024 + threadIdx.x * 4;
  int c = bsums[blockIdx.x];
#pragma unroll
  for (int j = 0; j < 4; j++) if (base + j < n) out[base + j] += c;
}

// ------- FUSED logit + segment softmax per (dst,relation) sub-segment.
// r10: pass_a wrote 19.2MB of logits that softmax immediately re-read — pure
// round-trip waste. The register-resident softmax now computes each logit
// itself (edat -> AS/aet gathers -> leaky-relu); pass_a8/pass_a1 deleted.
// Fallback (n>256, machine segments) computes logits inline in its max-pass.
template <int H>
__global__ void softpass_k(const int* __restrict__ rs, const int4* __restrict__ edat,
                           const float* __restrict__ aet, const float* __restrict__ AS,
                           float* __restrict__ lg) {
  int g = (int)((blockIdx.x * (size_t)blockDim.x + threadIdx.x) >> 6);
  int lane = threadIdx.x & 63;
  if (g >= kSeg) return;
  int start = rs[g], end = rs[g + 1];
  int n = (end - start) * H;
  if (n == 0) return;
  float* L = lg + (size_t)start * H;
  if (n <= 256) {
    float v[4];
#pragma unroll
    for (int j = 0; j < 4; j++) {
      int idx = lane + 64 * j;
      if (idx < n) {
        int p = start + ((H == 8) ? (idx >> 3) : idx);
        int h = (H == 8) ? (idx & 7) : 0;
        int4 ed = edat[p];
        int e = ed.x, sv = ed.y, dv = ed.z;
        int t = sv & 7;
        float val;
        if (H == 8) {
          val = AS[(size_t)(sv >> 3) * 80 + t * 8 + h]
              + AS[(size_t)(dv >> 3) * 80 + (5 + t) * 8 + h]
              + aet[(size_t)e * 8 + h];
        } else {
          val = AS[(size_t)(sv >> 3) * 16 + t]
              + AS[(size_t)(dv >> 3) * 16 + 5 + t]
              + aet[e];
        }
        v[j] = val > 0.f ? val : 0.2f * val;
      } else {
        v[j] = -3.0e38f;
      }
    }
    float m = fmaxf(fmaxf(v[0], v[1]), fmaxf(v[2], v[3]));
    if (H == 8) {
      m = fmaxf(m, __shfl_xor(m, 8));
      m = fmaxf(m, __shfl_xor(m, 16));
      m = fmaxf(m, __shfl_xor(m, 32));
    } else {
#pragma unroll
      for (int off = 1; off < 64; off <<= 1) m = fmaxf(m, __shfl_xor(m, off));
    }
    float s = 0.f;
#pragma unroll
    for (int j = 0; j < 4; j++) {
      v[j] = __expf(v[j] - m);   // masked lanes: exp(-huge) = 0
      s += v[j];
    }
    if (H == 8) {
      s += __shfl_xor(s, 8);
      s += __shfl_xor(s, 16);
      s += __shfl_xor(s, 32);
    } else {
#pragma unroll
      for (int off = 1; off < 64; off <<= 1) s += __shfl_xor(s, off);
    }
    float inv = 1.f / (s + 1e-16f);
#pragma unroll
    for (int j = 0; j < 4; j++) {
      int idx = lane + 64 * j;
      if (idx < n) L[idx] = v[j] * inv;
    }
    return;
  }
  // fallback (large machine segments): compute logits inline during max-pass
  float m = -3.0e38f;
  for (int idx = lane; idx < n; idx += 64) {
    int p = start + ((H == 8) ? (idx >> 3) : idx);
    int h = (H == 8) ? (idx & 7) : 0;
    int4 ed = edat[p];
    int e = ed.x, sv = ed.y, dv = ed.z;
    int t = sv & 7;
    float val;
    if (H == 8) {
      val = AS[(size_t)(sv >> 3) * 80 + t * 8 + h]
          + AS[(size_t)(dv >> 3) * 80 + (5 + t) * 8 + h]
          + aet[(size_t)e * 8 + h];
    } else {
      val = AS[(size_t)(sv >> 3) * 16 + t]
          + AS[(size_t)(dv >> 3) * 16 + 5 + t]
          + aet[e];
    }
    val = val > 0.f ? val : 0.2f * val;
    L[idx] = val;
    m = fmaxf(m, val);
  }
  if (H == 8) {
    m = fmaxf(m, __shfl_xor(m, 8));
    m = fmaxf(m, __shfl_xor(m, 16));
    m = fmaxf(m, __shfl_xor(m, 32));
  } else {
#pragma unroll
    for (int off = 1; off < 64; off <<= 1) m = fmaxf(m, __shfl_xor(m, off));
  }
  float s = 0.f;
  for (int idx = lane; idx < n; idx += 64) {
    float ex = __expf(L[idx] - m);
    L[idx] = ex;
    s += ex;
  }
  if (H == 8) {
    s += __shfl_xor(s, 8);
    s += __shfl_xor(s, 16);
    s += __shfl_xor(s, 32);
  } else {
#pragma unroll
    for (int off = 1; off < 64; off <<= 1) s += __shfl_xor(s, off);
  }
  float inv = 1.f / (s + 1e-16f);
  for (int idx = lane; idx < n; idx += 64) L[idx] *= inv;
}

// --------------- unified gather: agg[g] = sum over node's sub-segments of alpha*xs
template <int H>
__global__ void gat_gather_u(const int* __restrict__ rs, const int4* __restrict__ edat,
                             const float* __restrict__ alpha,
                             const unsigned short* __restrict__ xs,
                             float* __restrict__ agg) {
  int g = (int)((blockIdx.x * (size_t)blockDim.x + threadIdx.x) >> 6);
  int lane = threadIdx.x & 63;
  if (g >= kNTot) return;
  int start, end;
  if (g < 50000)      { start = rs[3 * g];              end = rs[3 * g + 3]; }
  else if (g < 51000) { int m = g - 50000; start = rs[150000 + m]; end = rs[150001 + m]; }
  else                { int j = g - 51000; start = rs[151000 + j]; end = rs[151001 + j]; }
  int deg = end - start;
  int l16 = lane & 15, quad = lane >> 4;
  int h = (H == 8) ? (l16 >> 1) : 0;
  float acc[8] = {0.f, 0.f, 0.f, 0.f, 0.f, 0.f, 0.f, 0.f};
  for (int base = 0; base < deg; base += 64) {
    int nchunk = deg - base; if (nchunk > 64) nchunk = 64;
    int sv = (lane < nchunk) ? edat[start + base + lane].w : 0;
    for (int i = 0; i < nchunk; i += 4) {
      int e = i + quad;
      bool act = e < nchunk;
      int s = __shfl(sv, act ? e : 0);
      float w = act ? alpha[(size_t)(start + base + e) * H + h] : 0.f;
      int4 raw = *(const int4*)(xs + (size_t)s * HID + l16 * 8);
      unsigned ua[4] = {(unsigned)raw.x, (unsigned)raw.y, (unsigned)raw.z, (unsigned)raw.w};
#pragma unroll
      for (int j = 0; j < 4; j++) {
        acc[2 * j]     += w * __uint_as_float(ua[j] << 16);
        acc[2 * j + 1] += w * __uint_as_float(ua[j] & 0xFFFF0000u);
      }
    }
  }
#pragma unroll
  for (int j = 0; j < 8; j++) {
    acc[j] += __shfl_xor(acc[j], 16);
    acc[j] += __shfl_xor(acc[j], 32);
  }
  if (quad == 0) {
    float* p = agg + (size_t)g * HID + l16 * 8;
    *(float4*)p = make_float4(acc[0], acc[1], acc[2], acc[3]);
    *(float4*)(p + 4) = make_float4(acc[4], acc[5], acc[6], acc[7]);
  }
}

// ------------------------------------------------- BatchNorm column stats
__global__ void colstats_b(const float* __restrict__ x, float* __restrict__ stats) {
  static constexpr int bpref[4] = {0, 384, 400, 448};
  static constexpr int rowoff[4] = {0, 50000, 51000, 56000};
  int b = blockIdx.x;
  int t = 0;
  while (t < 2 && b >= bpref[t + 1]) t++;
  int bl = b - bpref[t], nb = bpref[t + 1] - bpref[t];
  int tid = threadIdx.x;
  int col = tid & 127, half = tid >> 7;
  float s = 0.f, q = 0.f;
  for (int r = rowoff[t] + bl * 2 + half; r < rowoff[t + 1]; r += nb * 2) {
    float v = x[(size_t)r * HID + col];
    s += v; q += v * v;
  }
  __shared__ float ls[256], lq[256];
  ls[tid] = s; lq[tid] = q;
  __syncthreads();
  if (tid < 128) {
    s = ls[tid] + ls[tid + 128];
    q = lq[tid] + lq[tid + 128];
    unsafeAtomicAdd(&stats[t * 256 + col], s);
    unsafeAtomicAdd(&stats[t * 256 + 128 + col], q);
  }
}

// --- BN apply + ReLU + residual: fp32 agg (in-place -> new x) + bf16 shadow
__global__ void bn_apply_b(float* __restrict__ agg, const float* __restrict__ xold,
                           unsigned short* __restrict__ xnb, const float* __restrict__ stats,
                           const float* __restrict__ gammaL, const float* __restrict__ betaL,
                           int relu) {
  size_t i = blockIdx.x * (size_t)blockDim.x + threadIdx.x;
  if (i >= (size_t)kNTot * 32) return;
  int row = (int)(i >> 5);
  int t = (row < 50000) ? 0 : (row < 51000 ? 1 : 2);
  float invN = (t == 0) ? (1.f / 50000.f) : (t == 1 ? (1.f / 1000.f) : (1.f / 5000.f));
  const float* st = stats + t * 256;
  const float* gm = gammaL + t * HID;
  const float* bt = betaL + t * HID;
  int c4 = ((int)(i & 31)) * 4;
  float4 av = ((const float4*)agg)[i];
  float4 xv = ((const float4*)xold)[i];
  float a[4] = {av.x, av.y, av.z, av.w};
  float xo[4] = {xv.x, xv.y, xv.z, xv.w};
  float o[4];
#pragma unroll
  for (int j = 0; j < 4; j++) {
    int c = c4 + j;
    float mu = st[c] * invN;
    float var = st[128 + c] * invN - mu * mu;
    float g = gm[c] * rsqrtf(var + 1e-5f);
    float v = (a[j] - mu) * g + bt[c];
    if (relu) v = fmaxf(v, 0.f);
    o[j] = v + xo[j];
  }
  ((float4*)agg)[i] = make_float4(o[0], o[1], o[2], o[3]);
  ((ushort4*)xnb)[i] = make_ushort4(f2b(o[0]), f2b(o[1]), f2b(o[2]), f2b(o[3]));
}

// ============================================================== host driver
extern "C" void kernel_launch(void* const* d_in, const int* in_sizes, int n_in,
                              void* d_out, int out_size, void* d_ws, size_t ws_size,
                              hipStream_t stream) {
  const float* x_in[3] = {(const float*)d_in[0], (const float*)d_in[1], (const float*)d_in[2]};
  const int* ei[5];
  const float* ea[5];
  for (int t = 0; t < 5; t++) {
    ei[t] = (const int*)d_in[3 + 2 * t];
    ea[t] = (const float*)d_in[4 + 2 * t];
  }
  const float* Wn[3]  = {(const float*)d_in[13], (const float*)d_in[15], (const float*)d_in[17]};
  const float* bnb[3] = {(const float*)d_in[14], (const float*)d_in[16], (const float*)d_in[18]};
  const float* Wep   = (const float*)d_in[19];
  const float* bep   = (const float*)d_in[20];
  const float* Wg    = (const float*)d_in[21];
  const float* att_s = (const float*)d_in[22];
  const float* att_d = (const float*)d_in[23];
  const float* Wge   = (const float*)d_in[24];
  const float* att_e = (const float*)d_in[25];
  // d_in[26] = bg: cancelled exactly by BatchNorm mean-subtraction; unused.
  const float* gamma = (const float*)d_in[27];
  const float* beta  = (const float*)d_in[28];
  const float* Wo    = (const float*)d_in[29];
  const float* bo    = (const float*)d_in[30];

  float* ws = (float*)d_ws;
  size_t off = 0;
  auto alloc = [&](size_t n) { size_t o = off; off += (n + 255) & ~(size_t)255; return o; };
  auto allocb = [&](size_t n) { return alloc((n + 1) / 2); };

  float* bufA = ws + alloc((size_t)kNTot * HID);   // fp32 x (residual chain)
  float* bufB = ws + alloc((size_t)kNTot * HID);   // fp32 agg / next x
  unsigned short* xcurb = (unsigned short*)(ws + allocb((size_t)kNTot * HID));
  unsigned short* xs_all = (unsigned short*)(ws + allocb((size_t)kRTot * HID));
  unsigned short* WgT  = (unsigned short*)(ws + allocb((size_t)15 * HID * HID));
  unsigned short* WoT  = (unsigned short*)(ws + allocb((size_t)HID * HID));
  unsigned short* WnT_op  = (unsigned short*)(ws + allocb((size_t)HID * 64));
  unsigned short* WnT_ma  = (unsigned short*)(ws + allocb((size_t)HID * 32));
  unsigned short* WnT_job = (unsigned short*)(ws + allocb((size_t)HID * 32));
  unsigned short* VbT  = (unsigned short*)(ws + allocb((size_t)3 * 80 * HID));
  unsigned short* Wfh  = (unsigned short*)(ws + allocb((size_t)5 * 32 * 32));
  unsigned short* Wfl  = (unsigned short*)(ws + allocb((size_t)5 * 32 * 32));
  float* ccv    = ws + alloc((size_t)5 * 32);
  float* Sv     = ws + alloc((size_t)15 * 8 * HID);
  float* Dv     = ws + alloc((size_t)15 * 8 * HID);
  float* w32    = ws + alloc((size_t)15 * 8 * 32);
  float* cv     = ws + alloc((size_t)15 * 8);
  float* stats  = ws + alloc((size_t)3 * 256);
  float* ASbuf  = ws + alloc((size_t)kNTot * 80);
  float* logits = ws + alloc((size_t)kETot * 8 + 64);
  int* rs_all   = (int*)(ws + alloc((size_t)kSeg + 8));
  int4* edat    = (int4*)(ws + alloc((size_t)kETot * 4));  // {e, spack, dpack, ssrc}
  float* aet0   = ws + alloc((size_t)kETot * 8);   // edge-order a_e, layer 0 (H=8)
  float* aet1   = ws + alloc((size_t)kETot * 8);   // layer 1 (H=8)
  float* aet2   = ws + alloc((size_t)kETot);       // layer 2 (H=1)
  // aliases: xinb_* live inside xs_all (consumed before xs_all is written);
  // cnt/rank/bsums live inside logits (CSR build precedes first logit write)
  unsigned short* xinb_op  = xs_all;                          // 3.2M ushorts
  unsigned short* xinb_ma  = xs_all + 3200000;                // 32k ushorts
  unsigned short* xinb_job = xs_all + 3232000;                // 160k ushorts
  int* cnt    = (int*)logits;                       // 156,032 ints
  int* rank   = (int*)(logits + 156032);            // 600,000 ints
  int* bsums  = (int*)(logits + 756288);            // 160 ints
  (void)ws_size; (void)in_sizes; (void)n_in; (void)out_size;

  float* xcur = bufA;
  float* agg  = bufB;

  EdgeJobs EJ;
  for (int t = 0; t < 5; t++) { EJ.src[t] = ei[t]; EJ.dst[t] = ei[t] + kEsz[t]; }

  // -------- prologue: fold tables (needed by mega1) + cnt zero
  hipMemsetAsync(cnt, 0, (size_t)kSeg * 4, stream);
  fold_kernel<<<120, 128, 0, stream>>>(Wg, att_s, att_d, Wge, att_e, Wep, bep,
                                       Sv, Dv, w32, cv);
  build_vb<<<(3 * 80 * HID + 255) / 256, 256, 0, stream>>>(Sv, Dv, VbT);
  build_wf<<<(5 * 32 * 32 + 255) / 256, 256, 0, stream>>>(w32, cv, Wfh, Wfl, ccv);

  // -------- MEGA1: fold_ae ∪ hist_rank, 4:1 interleaved (latency hides under BW)
  Mega1Args MA;
  for (int t = 0; t < 5; t++) { MA.ea[t] = ea[t]; MA.dst[t] = ei[t] + kEsz[t]; }
  fold_hist<<<11720, 256, 0, stream>>>(MA, Wfh, Wfl, ccv, aet0, aet1, aet2, cnt, rank);

  // -------- CSR scan + scatter
  int nb = (kSeg + 1023) / 1024;
  scan_blocks<<<nb, 256, 0, stream>>>(cnt, rs_all, bsums, kSeg);
  scan_carry<<<1, 64, 0, stream>>>(bsums, nb, rs_all + kSeg);
  scan_add<<<nb, 256, 0, stream>>>(rs_all, bsums, kSeg);
  scatter_b<<<(kETot + 255) / 256, 256, 0, stream>>>(EJ, rs_all, rank, edat);

  // -------- bf16 conversions
  conv_pad<<<(kNOp * 64 + 255) / 256, 256, 0, stream>>>(x_in[0], xinb_op, kNOp, 64, 64);
  conv_pad<<<(kNMa * 32 + 255) / 256, 256, 0, stream>>>(x_in[1], xinb_ma, kNMa, 32, 32);
  conv_pad<<<(kNJob * 32 + 255) / 256, 256, 0, stream>>>(x_in[2], xinb_job, kNJob, 16, 32);
  transpose_w<<<(HID * 64 + 255) / 256, 256, 0, stream>>>(Wn[0], WnT_op, 64, HID, 64, 1);
  transpose_w<<<(HID * 32 + 255) / 256, 256, 0, stream>>>(Wn[1], WnT_ma, 32, HID, 32, 1);
  transpose_w<<<(HID * 32 + 255) / 256, 256, 0, stream>>>(Wn[2], WnT_job, 16, HID, 32, 1);
  transpose_w<<<(15 * HID * HID + 255) / 256, 256, 0, stream>>>(Wg, WgT, HID, HID, HID, 15);
  transpose_w<<<(HID * HID + 255) / 256, 256, 0, stream>>>(Wo, WoT, HID, HID, HID, 1);

  // -------- node input projections (fp32 x + bf16 shadow)
  gemm_mfma<2><<<((kNOp + 15) / 16 + 3) / 4, 256, 0, stream>>>(
      xinb_op, WnT_op, bnb[0], xcur, xcurb, kNOp);
  gemm_mfma<1><<<((kNMa + 15) / 16 + 3) / 4, 256, 0, stream>>>(
      xinb_ma, WnT_ma, bnb[1], xcur + (size_t)50000 * HID, xcurb + (size_t)50000 * HID, kNMa);
  gemm_mfma<1><<<((kNJob + 15) / 16 + 3) / 4, 256, 0, stream>>>(
      xinb_job, WnT_job, bnb[2], xcur + (size_t)51000 * HID, xcurb + (size_t)51000 * HID, kNJob);

  for (int l = 0; l < 3; l++) {
    int H = (l < 2) ? 8 : 1;

    // xs for all 5 relations; LDS-staged weights, LDS-bounced coalesced stores
    gemm_xs<<<877, 256, 0, stream>>>(xcurb, WgT + (size_t)l * 5 * HID * HID, xs_all);

    // a_s/a_d for all (relation, head) via one MFMA GEMM
    int asBlocks = ((kNTot + 15) / 16 + 3) / 4;
    if (H == 8)
      gemm_as<80><<<asBlocks, 256, 0, stream>>>(xcurb, VbT + (size_t)l * 80 * HID, ASbuf, kNTot);
    else
      gemm_as<16><<<asBlocks, 256, 0, stream>>>(xcurb, VbT + (size_t)l * 80 * HID, ASbuf, kNTot);

    // fused logit + softmax (pass_a deleted), then gather
    if (H == 8) {
      const float* aeL = (l == 0) ? aet0 : aet1;
      softpass_k<8><<<((size_t)kSeg * 64 + 255) / 256, 256, 0, stream>>>(
          rs_all, edat, aeL, ASbuf, logits);
      gat_gather_u<8><<<((size_t)kNTot * 64 + 255) / 256, 256, 0, stream>>>(
          rs_all, edat, logits, xs_all, agg);
    } else {
      softpass_k<1><<<((size_t)kSeg * 64 + 255) / 256, 256, 0, stream>>>(
          rs_all, edat, aet2, ASbuf, logits);
      gat_gather_u<1><<<((size_t)kNTot * 64 + 255) / 256, 256, 0, stream>>>(
          rs_all, edat, logits, xs_all, agg);
    }

    hipMemsetAsync(stats, 0, 3 * 256 * 4, stream);
    colstats_b<<<448, 256, 0, stream>>>(agg, stats);
    bn_apply_b<<<(unsigned)(((size_t)kNTot * 32 + 255) / 256), 256, 0, stream>>>(
        agg, xcur, xcurb, stats, gamma + (size_t)l * 3 * HID, beta + (size_t)l * 3 * HID,
        (l < 2) ? 1 : 0);
    float* tmp = xcur; xcur = agg; agg = tmp;   // agg now holds new fp32 x
  }

  gemm_mfma<4><<<((kNOp + 15) / 16 + 3) / 4, 256, 0, stream>>>(
      xcurb, WoT, bo, (float*)d_out, nullptr, kNOp);
}